// Round 5
// baseline (31926.227 us; speedup 1.0000x reference)
//
#include <hip/hip_runtime.h>
#include <cmath>

namespace {

constexpr int Tn = 64;
constexpr int Bn = 512;
constexpr int Xn = 784;
constexpr int XnP = 800;
constexpr int Fn = 64;
constexpr int Zn = 64;
constexpr int Hn = 512;
constexpr int NB = 256;   // persistent grid blocks (1 per CU guaranteed resident)
constexpr int NTH = 256;  // threads per block

typedef unsigned short us;
typedef __attribute__((ext_vector_type(8))) short bf16x8;
typedef __attribute__((ext_vector_type(4))) float f32x4;

__device__ __forceinline__ us f2b(float v) {
  unsigned int u = __float_as_uint(v);
  return (us)((u + 0x7FFFu + ((u >> 16) & 1u)) >> 16);
}
__device__ __forceinline__ float b2f(us u) { return __uint_as_float(((unsigned int)u) << 16); }
__device__ __forceinline__ float sigmf(float v) { return 1.0f / (1.0f + __expf(-v)); }
__device__ __forceinline__ float splusf(float v) {
  return v > 0.0f ? (v + log1pf(__expf(-v))) : log1pf(__expf(v));
}
// returns the block total on tid 0, 0.0f on all other threads
__device__ __forceinline__ float block_sum(float v, float* red) {
  #pragma unroll
  for (int off = 32; off > 0; off >>= 1) v += __shfl_down(v, off, 64);
  if ((threadIdx.x & 63) == 0) red[threadIdx.x >> 6] = v;
  __syncthreads();
  float s = 0.0f;
  if (threadIdx.x == 0) s = red[0] + red[1] + red[2] + red[3];
  return s;
}

// ---- lean grid barrier (replaces cg::grid_group::sync; ~10x cheaper) ----
// bar[0] = arrive counter, bar[32] = generation (128 B apart).
// Protocol: __syncthreads (compiler drains vmcnt before s_barrier, so all
// waves' stores are issued) -> wave0: release fence (L2 writeback), arrive
// via device-scope atomic, spin on generation, acquire fence (invalidate)
// -> __syncthreads releases the other waves after the invalidate.
__device__ __forceinline__ void gsync(int* bar) {
  __syncthreads();
  if (threadIdx.x == 0) {
    int* cnt = bar;
    int* gen = bar + 32;
    __builtin_amdgcn_fence(__ATOMIC_RELEASE, "agent");
    const int g = __hip_atomic_load(gen, __ATOMIC_RELAXED, __HIP_MEMORY_SCOPE_AGENT);
    if (__hip_atomic_fetch_add(cnt, 1, __ATOMIC_ACQ_REL, __HIP_MEMORY_SCOPE_AGENT) == NB - 1) {
      __hip_atomic_store(cnt, 0, __ATOMIC_RELAXED, __HIP_MEMORY_SCOPE_AGENT);
      __hip_atomic_fetch_add(gen, 1, __ATOMIC_RELEASE, __HIP_MEMORY_SCOPE_AGENT);
    } else {
      while (__hip_atomic_load(gen, __ATOMIC_ACQUIRE, __HIP_MEMORY_SCOPE_AGENT) == g)
        __builtin_amdgcn_s_sleep(1);
    }
    __builtin_amdgcn_fence(__ATOMIC_ACQUIRE, "agent");
  }
  __syncthreads();
}

struct KParams {
  // fp32 inputs
  const float *x, *eps_f, *eps_z;
  const float *f_pxW1, *pxb1, *f_pxW2, *pxb2;
  const float *f_pzW, *pzb, *f_pfW, *pfb;
  const float *f_rWih, *f_rWhh, *rbih, *rbhh;
  const float *f_zpW, *zpb, *f_zpmW, *zpmb, *f_zpsW, *zpsb;
  const float *f_feWih, *f_feWhh, *febih, *febhh;
  const float *f_femW, *femb, *f_fesW, *fesb;
  const float *f_zeW1, *zeb1, *f_zeW2, *zeb2, *f_zemW, *zemb, *f_zesW, *zesb;
  const float *f_dW1, *db1, *f_dW2, *db2, *f_dmW, *dmb;
  float* out;
  // bf16 weights (workspace)
  us *b_pxW1, *b_pxW2, *b_pzW, *b_pfW, *b_rWih, *b_rWhh, *b_zpW, *b_zpmW, *b_zpsW;
  us *b_feWih, *b_feWhh, *b_femW, *b_fesW, *b_zeW1, *b_zeW2, *b_zemW, *b_zesW;
  us *b_dW1, *b_dW2, *b_dmW;
  // activations (workspace)
  us *phi_x, *fh_a, *fh_b, *fbuf, *phi_f, *h_a, *h_b;
  us *zp, *zepre, *ze, *phiz, *dtmp, *dec;
  float *zpm, *zps, *Cpre_gru, *Cpre_dec, *gipre, *ghpre, *dtmph;
  float *parts;   // [0..7]=z_kld partials, [8..15]=f_kld partials
  int *bar;       // grid barrier state (zeroed before launch)
  us *xch, *tmpb;
  int CH;
};

// ================= tile device functions =================
// 64x64 GEMM tile with optional fp32 accumulator init, fp32/bf16 out, bias, relu.
// smem >= 10240 B.
template <int NSEG, bool RELU, bool F32OUT, bool HASINIT, bool HASBIAS>
__device__ void tile_gemmx(
    int bx, int by,
    const us* A0, const us* W0, int ldw0, int K0,
    const us* A1, const us* W1, int ldw1, int K1,
    const float* initC, int ldi, const float* bias,
    void* Cout, int ldc, char* smemc)
{
  us* As = (us*)smemc; us* Bs = (us*)(smemc + 5120);
  const int tid = threadIdx.x, srow = tid >> 2, scb = (tid & 3) * 8;
  const int lane = tid & 63, w = tid >> 6, l15 = lane & 15, q = lane >> 4;
  const int m0 = by * 64, n0 = bx * 64;
  f32x4 acc[4];
  if (HASINIT) {
    #pragma unroll
    for (int j = 0; j < 4; ++j)
      #pragma unroll
      for (int r = 0; r < 4; ++r)
        acc[j][r] = initC[(size_t)(m0 + w * 16 + q * 4 + r) * ldi + n0 + j * 16 + l15];
  } else {
    #pragma unroll
    for (int j = 0; j < 4; ++j) acc[j] = (f32x4){0.f, 0.f, 0.f, 0.f};
  }
  #pragma unroll
  for (int seg = 0; seg < NSEG; ++seg) {
    const us* A = (seg == 0) ? A0 : A1;
    const us* W = (seg == 0) ? W0 : W1;
    const int ldw = (seg == 0) ? ldw0 : ldw1;
    const int K   = (seg == 0) ? K0 : K1;
    const us* ap = A + (size_t)(m0 + srow) * K + scb;
    const us* wp = W + (size_t)(n0 + srow) * ldw + scb;
    uint4 av = *(const uint4*)ap;
    uint4 wv = *(const uint4*)wp;
    for (int k0 = 0; k0 < K; k0 += 32) {
      __syncthreads();
      *(uint4*)&As[srow * 40 + scb] = av;
      *(uint4*)&Bs[srow * 40 + scb] = wv;
      __syncthreads();
      if (k0 + 32 < K) {
        av = *(const uint4*)(ap + k0 + 32);
        wv = *(const uint4*)(wp + k0 + 32);
      }
      bf16x8 a = *(const bf16x8*)&As[(w * 16 + l15) * 40 + q * 8];
      #pragma unroll
      for (int j = 0; j < 4; ++j) {
        bf16x8 b = *(const bf16x8*)&Bs[(j * 16 + l15) * 40 + q * 8];
        acc[j] = __builtin_amdgcn_mfma_f32_16x16x32_bf16(a, b, acc[j], 0, 0, 0);
      }
    }
  }
  #pragma unroll
  for (int j = 0; j < 4; ++j) {
    const int col = n0 + j * 16 + l15;
    const float bv = HASBIAS ? bias[col] : 0.f;
    #pragma unroll
    for (int r = 0; r < 4; ++r) {
      const int row = m0 + w * 16 + q * 4 + r;
      float v = acc[j][r] + bv;
      if (RELU) v = fmaxf(v, 0.f);
      if (F32OUT) ((float*)Cout)[(size_t)row * ldc + col] = v;
      else        ((us*)Cout)[(size_t)row * ldc + col] = f2b(v);
    }
  }
}

// 3-gate GEMM: out[row][{c,512+c,1024+c}] (+= init) = A @ Wgate^T for gates at
// W rows {c, 512+c, 1024+c}, K=Hn.  out is fp32 [Bn][1536]. smem >= 20480 B.
template <bool HASINIT>
__device__ void tile_g3(int bx, int by, const us* A, const us* W, int ldw,
                        const float* initC, float* outC, char* smemc)
{
  us* Asm = (us*)smemc; us* Rs = (us*)(smemc + 5120);
  us* Zs = (us*)(smemc + 10240); us* Ns = (us*)(smemc + 15360);
  const int tid = threadIdx.x, srow = tid >> 2, scb = (tid & 3) * 8;
  const int lane = tid & 63, w = tid >> 6, l15 = lane & 15, q = lane >> 4;
  const int m0 = by * 64, c0 = bx * 64;
  f32x4 aR[4], aZ[4], aN[4];
  if (HASINIT) {
    #pragma unroll
    for (int j = 0; j < 4; ++j) {
      const int c = c0 + j * 16 + l15;
      #pragma unroll
      for (int r = 0; r < 4; ++r) {
        const size_t row = (size_t)(m0 + w * 16 + q * 4 + r) * 1536;
        aR[j][r] = initC[row + c];
        aZ[j][r] = initC[row + 512 + c];
        aN[j][r] = initC[row + 1024 + c];
      }
    }
  } else {
    #pragma unroll
    for (int j = 0; j < 4; ++j) {
      aR[j] = (f32x4){0.f, 0.f, 0.f, 0.f}; aZ[j] = aR[j]; aN[j] = aR[j];
    }
  }
  const us* ap = A + (size_t)(m0 + srow) * Hn + scb;
  const us* wr = W + (size_t)(c0 + srow) * ldw + scb;
  const us* wz = wr + (size_t)512 * ldw;
  const us* wn = wz + (size_t)512 * ldw;
  uint4 av = *(const uint4*)ap;
  uint4 rv = *(const uint4*)wr;
  uint4 zv = *(const uint4*)wz;
  uint4 nv = *(const uint4*)wn;
  for (int k0 = 0; k0 < Hn; k0 += 32) {
    __syncthreads();
    *(uint4*)&Asm[srow * 40 + scb] = av;
    *(uint4*)&Rs[srow * 40 + scb] = rv;
    *(uint4*)&Zs[srow * 40 + scb] = zv;
    *(uint4*)&Ns[srow * 40 + scb] = nv;
    __syncthreads();
    if (k0 + 32 < Hn) {
      av = *(const uint4*)(ap + k0 + 32);
      rv = *(const uint4*)(wr + k0 + 32);
      zv = *(const uint4*)(wz + k0 + 32);
      nv = *(const uint4*)(wn + k0 + 32);
    }
    bf16x8 a = *(const bf16x8*)&Asm[(w * 16 + l15) * 40 + q * 8];
    #pragma unroll
    for (int j = 0; j < 4; ++j) {
      bf16x8 br = *(const bf16x8*)&Rs[(j * 16 + l15) * 40 + q * 8];
      bf16x8 bz = *(const bf16x8*)&Zs[(j * 16 + l15) * 40 + q * 8];
      bf16x8 bn = *(const bf16x8*)&Ns[(j * 16 + l15) * 40 + q * 8];
      aR[j] = __builtin_amdgcn_mfma_f32_16x16x32_bf16(a, br, aR[j], 0, 0, 0);
      aZ[j] = __builtin_amdgcn_mfma_f32_16x16x32_bf16(a, bz, aZ[j], 0, 0, 0);
      aN[j] = __builtin_amdgcn_mfma_f32_16x16x32_bf16(a, bn, aN[j], 0, 0, 0);
    }
  }
  #pragma unroll
  for (int j = 0; j < 4; ++j) {
    const int c = c0 + j * 16 + l15;
    #pragma unroll
    for (int r = 0; r < 4; ++r) {
      const size_t row = (size_t)(m0 + w * 16 + q * 4 + r) * 1536;
      outC[row + c] = aR[j][r];
      outC[row + 512 + c] = aZ[j][r];
      outC[row + 1024 + c] = aN[j][r];
    }
  }
}

// Phase-B GRU step tile: gh = h @ Whh^T (3 gates) fused with precomputed gi
// (fp32 [Bn][1536]) and gate math. smem >= 20480 B.
__device__ void tile_ghgates(int bx, int by, const us* hprev, const us* Whh,
    const float* gi, const float* bih, const float* bhh, us* hnew, char* smemc)
{
  us* Asm = (us*)smemc; us* Rs = (us*)(smemc + 5120);
  us* Zs = (us*)(smemc + 10240); us* Ns = (us*)(smemc + 15360);
  const int tid = threadIdx.x, srow = tid >> 2, scb = (tid & 3) * 8;
  const int lane = tid & 63, w = tid >> 6, l15 = lane & 15, q = lane >> 4;
  const int m0 = by * 64, c0 = bx * 64;
  f32x4 aR[4], aZ[4], aH[4];
  #pragma unroll
  for (int j = 0; j < 4; ++j) {
    aR[j] = (f32x4){0.f, 0.f, 0.f, 0.f}; aZ[j] = aR[j]; aH[j] = aR[j];
  }
  const us* ap = hprev + (size_t)(m0 + srow) * Hn + scb;
  const us* wr = Whh + (size_t)(c0 + srow) * Hn + scb;
  const us* wz = wr + (size_t)512 * Hn;
  const us* wn = wz + (size_t)512 * Hn;
  uint4 av = *(const uint4*)ap;
  uint4 rv = *(const uint4*)wr;
  uint4 zv = *(const uint4*)wz;
  uint4 nv = *(const uint4*)wn;
  for (int k0 = 0; k0 < Hn; k0 += 32) {
    __syncthreads();
    *(uint4*)&Asm[srow * 40 + scb] = av;
    *(uint4*)&Rs[srow * 40 + scb] = rv;
    *(uint4*)&Zs[srow * 40 + scb] = zv;
    *(uint4*)&Ns[srow * 40 + scb] = nv;
    __syncthreads();
    if (k0 + 32 < Hn) {
      av = *(const uint4*)(ap + k0 + 32);
      rv = *(const uint4*)(wr + k0 + 32);
      zv = *(const uint4*)(wz + k0 + 32);
      nv = *(const uint4*)(wn + k0 + 32);
    }
    bf16x8 a = *(const bf16x8*)&Asm[(w * 16 + l15) * 40 + q * 8];
    #pragma unroll
    for (int j = 0; j < 4; ++j) {
      bf16x8 br = *(const bf16x8*)&Rs[(j * 16 + l15) * 40 + q * 8];
      bf16x8 bz = *(const bf16x8*)&Zs[(j * 16 + l15) * 40 + q * 8];
      bf16x8 bn = *(const bf16x8*)&Ns[(j * 16 + l15) * 40 + q * 8];
      aR[j] = __builtin_amdgcn_mfma_f32_16x16x32_bf16(a, br, aR[j], 0, 0, 0);
      aZ[j] = __builtin_amdgcn_mfma_f32_16x16x32_bf16(a, bz, aZ[j], 0, 0, 0);
      aH[j] = __builtin_amdgcn_mfma_f32_16x16x32_bf16(a, bn, aH[j], 0, 0, 0);
    }
  }
  #pragma unroll
  for (int j = 0; j < 4; ++j) {
    const int c = c0 + j * 16 + l15;
    const float bR = bih[c] + bhh[c];
    const float bZ = bih[Hn + c] + bhh[Hn + c];
    const float bI = bih[2 * Hn + c];
    const float bH = bhh[2 * Hn + c];
    #pragma unroll
    for (int r = 0; r < 4; ++r) {
      const int m = m0 + w * 16 + q * 4 + r;
      const size_t grow = (size_t)m * 1536;
      const float h = b2f(hprev[(size_t)m * Hn + c]);
      const float rg = sigmf(gi[grow + c] + aR[j][r] + bR);
      const float zg = sigmf(gi[grow + 512 + c] + aZ[j][r] + bZ);
      const float ng = tanhf(gi[grow + 1024 + c] + bI + rg * (aH[j][r] + bH));
      hnew[(size_t)m * Hn + c] = f2b((1.0f - zg) * ng + zg * h);
    }
  }
}

// Phase-D GRU final tile.
__device__ void tile_gru_fin(
    int bx, int by,
    const us* phiz, const us* rWih,
    const float* gipre, const float* ghpre,
    const us* hprev,
    const float* bih, const float* bhh,
    us* hnew, char* smemc)
{
  us* Asm = (us*)smemc; us* Rs = (us*)(smemc + 5120);
  us* Zs = (us*)(smemc + 10240); us* Ns = (us*)(smemc + 15360);
  const int tid = threadIdx.x, srow = tid >> 2, scb = (tid & 3) * 8;
  const int lane = tid & 63, w = tid >> 6, l15 = lane & 15, q = lane >> 4;
  const int m0 = by * 64, c0 = bx * 64;
  f32x4 aR[4], aZ[4], aI[4];
  float aH[4][4];
  #pragma unroll
  for (int j = 0; j < 4; ++j) {
    const int c = c0 + j * 16 + l15;
    #pragma unroll
    for (int r = 0; r < 4; ++r) {
      const size_t row = (size_t)(m0 + w * 16 + q * 4 + r) * 1536;
      aR[j][r] = gipre[row + c] + ghpre[row + c];
      aZ[j][r] = gipre[row + 512 + c] + ghpre[row + 512 + c];
      aI[j][r] = gipre[row + 1024 + c];
      aH[j][r] = ghpre[row + 1024 + c];
    }
  }
  const us* ap = phiz + (size_t)(m0 + srow) * Hn + scb;
  const us* wr = rWih + (size_t)(c0 + srow) * 1536 + 512 + scb;
  const us* wz = wr + (size_t)512 * 1536;
  const us* wn = wz + (size_t)512 * 1536;
  uint4 av = *(const uint4*)ap;
  uint4 rv = *(const uint4*)wr;
  uint4 zv = *(const uint4*)wz;
  uint4 nv = *(const uint4*)wn;
  for (int k0 = 0; k0 < Hn; k0 += 32) {
    __syncthreads();
    *(uint4*)&Asm[srow * 40 + scb] = av;
    *(uint4*)&Rs[srow * 40 + scb] = rv;
    *(uint4*)&Zs[srow * 40 + scb] = zv;
    *(uint4*)&Ns[srow * 40 + scb] = nv;
    __syncthreads();
    if (k0 + 32 < Hn) {
      av = *(const uint4*)(ap + k0 + 32);
      rv = *(const uint4*)(wr + k0 + 32);
      zv = *(const uint4*)(wz + k0 + 32);
      nv = *(const uint4*)(wn + k0 + 32);
    }
    bf16x8 a = *(const bf16x8*)&Asm[(w * 16 + l15) * 40 + q * 8];
    #pragma unroll
    for (int j = 0; j < 4; ++j) {
      bf16x8 br = *(const bf16x8*)&Rs[(j * 16 + l15) * 40 + q * 8];
      bf16x8 bz = *(const bf16x8*)&Zs[(j * 16 + l15) * 40 + q * 8];
      bf16x8 bn = *(const bf16x8*)&Ns[(j * 16 + l15) * 40 + q * 8];
      aR[j] = __builtin_amdgcn_mfma_f32_16x16x32_bf16(a, br, aR[j], 0, 0, 0);
      aZ[j] = __builtin_amdgcn_mfma_f32_16x16x32_bf16(a, bz, aZ[j], 0, 0, 0);
      aI[j] = __builtin_amdgcn_mfma_f32_16x16x32_bf16(a, bn, aI[j], 0, 0, 0);
    }
  }
  #pragma unroll
  for (int j = 0; j < 4; ++j) {
    const int c = c0 + j * 16 + l15;
    const float bR = bih[c] + bhh[c];
    const float bZ = bih[Hn + c] + bhh[Hn + c];
    const float bI = bih[2 * Hn + c];
    const float bH = bhh[2 * Hn + c];
    #pragma unroll
    for (int r = 0; r < 4; ++r) {
      const int m = m0 + w * 16 + q * 4 + r;
      const float h = b2f(hprev[(size_t)m * Hn + c]);
      const float rg = sigmf(aR[j][r] + bR);
      const float zg = sigmf(aZ[j][r] + bZ);
      const float ng = tanhf(aI[j][r] + bI + rg * (aH[j][r] + bH));
      hnew[(size_t)m * Hn + c] = f2b((1.0f - zg) * ng + zg * h);
    }
  }
}

// dual-head stats tile, MODE 0 (prior heads -> fp32) / MODE 1 (f stats).
// MODE 1 returns 0.5*kld on tid 0 (0.0f elsewhere). smem >= 15376 B.
template <int MODE>
__device__ float stat_dual(int vb,
    const us* Ain, const us* Wm, const float* bm, const us* Ws, const float* bs,
    const float* eps,
    us* o0b, float* o_pm, float* o_ps, char* smemc)
{
  us* As = (us*)smemc; us* Ms = (us*)(smemc + 5120); us* Ss = (us*)(smemc + 10240);
  float* red = (float*)(smemc + 15360);
  const int tid = threadIdx.x, srow = tid >> 2, scb = (tid & 3) * 8;
  const int lane = tid & 63, w = tid >> 6, l15 = lane & 15, q = lane >> 4;
  const int m0 = vb * 64;
  f32x4 am[4], as_[4];
  #pragma unroll
  for (int j = 0; j < 4; ++j) { am[j] = (f32x4){0.f, 0.f, 0.f, 0.f}; as_[j] = am[j]; }
  const us* ap = Ain + (size_t)(m0 + srow) * Hn + scb;
  const us* mp = Wm + (size_t)srow * Hn + scb;
  const us* sp = Ws + (size_t)srow * Hn + scb;
  uint4 av = *(const uint4*)ap;
  uint4 mv = *(const uint4*)mp;
  uint4 sv = *(const uint4*)sp;
  for (int k0 = 0; k0 < Hn; k0 += 32) {
    __syncthreads();
    *(uint4*)&As[srow * 40 + scb] = av;
    *(uint4*)&Ms[srow * 40 + scb] = mv;
    *(uint4*)&Ss[srow * 40 + scb] = sv;
    __syncthreads();
    if (k0 + 32 < Hn) {
      av = *(const uint4*)(ap + k0 + 32);
      mv = *(const uint4*)(mp + k0 + 32);
      sv = *(const uint4*)(sp + k0 + 32);
    }
    bf16x8 a = *(const bf16x8*)&As[(w * 16 + l15) * 40 + q * 8];
    #pragma unroll
    for (int j = 0; j < 4; ++j) {
      bf16x8 b0 = *(const bf16x8*)&Ms[(j * 16 + l15) * 40 + q * 8];
      bf16x8 b1 = *(const bf16x8*)&Ss[(j * 16 + l15) * 40 + q * 8];
      am[j]  = __builtin_amdgcn_mfma_f32_16x16x32_bf16(a, b0, am[j], 0, 0, 0);
      as_[j] = __builtin_amdgcn_mfma_f32_16x16x32_bf16(a, b1, as_[j], 0, 0, 0);
    }
  }
  float kld = 0.0f;
  #pragma unroll
  for (int j = 0; j < 4; ++j) {
    const int c = j * 16 + l15;
    const float bmv = bm[c], bsv = bs[c];
    #pragma unroll
    for (int r = 0; r < 4; ++r) {
      const int m = m0 + w * 16 + q * 4 + r;
      const float mu = am[j][r] + bmv;
      const float sd = splusf(as_[j][r] + bsv);
      if (MODE == 0) {
        o_pm[(size_t)m * Zn + c] = mu;
        o_ps[(size_t)m * Zn + c] = sd;
      } else {
        o0b[(size_t)m * Zn + c] = f2b(eps[(size_t)m * Zn + c] * sd + mu);
        kld += mu * mu + sd * sd - 2.0f * __logf(sd) - 1.0f;
      }
    }
  }
  if (MODE != 0) return 0.5f * block_sum(kld, red);
  return 0.0f;
}

// zestat fused with phiz = relu(zt @ pzW^T + pzb). smem >= 20480 B.
// Returns 0.5*kld partial on tid 0 (0.0f elsewhere).
__device__ float tile_zestat_phiz(int vb,
    const us* ze, const us* Wm, const float* bm, const us* Ws, const float* bs,
    const float* eps, const float* pm_in, const float* ps_in,
    const us* pzW, const float* pzb, us* phiz,
    char* smemc)
{
  us* As = (us*)smemc; us* Ms = (us*)(smemc + 5120); us* Ss = (us*)(smemc + 10240);
  float* red = (float*)(smemc + 15360);
  const int tid = threadIdx.x, srow = tid >> 2, scb = (tid & 3) * 8;
  const int lane = tid & 63, w = tid >> 6, l15 = lane & 15, q = lane >> 4;
  const int m0 = vb * 64;
  f32x4 am[4], as_[4];
  #pragma unroll
  for (int j = 0; j < 4; ++j) { am[j] = (f32x4){0.f, 0.f, 0.f, 0.f}; as_[j] = am[j]; }
  const us* ap = ze + (size_t)(m0 + srow) * Hn + scb;
  const us* mp = Wm + (size_t)srow * Hn + scb;
  const us* sp = Ws + (size_t)srow * Hn + scb;
  uint4 av = *(const uint4*)ap;
  uint4 mv = *(const uint4*)mp;
  uint4 sv = *(const uint4*)sp;
  for (int k0 = 0; k0 < Hn; k0 += 32) {
    __syncthreads();
    *(uint4*)&As[srow * 40 + scb] = av;
    *(uint4*)&Ms[srow * 40 + scb] = mv;
    *(uint4*)&Ss[srow * 40 + scb] = sv;
    __syncthreads();
    if (k0 + 32 < Hn) {
      av = *(const uint4*)(ap + k0 + 32);
      mv = *(const uint4*)(mp + k0 + 32);
      sv = *(const uint4*)(sp + k0 + 32);
    }
    bf16x8 a = *(const bf16x8*)&As[(w * 16 + l15) * 40 + q * 8];
    #pragma unroll
    for (int j = 0; j < 4; ++j) {
      bf16x8 b0 = *(const bf16x8*)&Ms[(j * 16 + l15) * 40 + q * 8];
      bf16x8 b1 = *(const bf16x8*)&Ss[(j * 16 + l15) * 40 + q * 8];
      am[j]  = __builtin_amdgcn_mfma_f32_16x16x32_bf16(a, b0, am[j], 0, 0, 0);
      as_[j] = __builtin_amdgcn_mfma_f32_16x16x32_bf16(a, b1, as_[j], 0, 0, 0);
    }
  }
  float kld = 0.0f;
  us ztv[4][4];
  #pragma unroll
  for (int j = 0; j < 4; ++j) {
    const int c = j * 16 + l15;
    const float bmv = bm[c], bsv = bs[c];
    #pragma unroll
    for (int r = 0; r < 4; ++r) {
      const int m = m0 + w * 16 + q * 4 + r;
      const float mu = am[j][r] + bmv;
      const float sd = splusf(as_[j][r] + bsv);
      ztv[j][r] = f2b(eps[(size_t)m * Zn + c] * sd + mu);
      const float pm = pm_in[(size_t)m * Zn + c];
      const float ps = ps_in[(size_t)m * Zn + c];
      const float dd = (mu - pm) / ps;
      const float rr = sd / ps;
      kld += dd * dd + rr * rr - 2.0f * __logf(rr) - 1.0f;
    }
  }
  const float kout = 0.5f * block_sum(kld, red);
  us* zts = (us*)smemc;              // 64*72*2 = 9216 B (overlaps As+Ms)
  us* Bs = (us*)(smemc + 10240);     // overlaps Ss
  #pragma unroll
  for (int j = 0; j < 4; ++j)
    #pragma unroll
    for (int r = 0; r < 4; ++r)
      zts[(w * 16 + q * 4 + r) * 72 + (j * 16 + l15)] = ztv[j][r];
  for (int nt = 0; nt < 8; ++nt) {
    f32x4 pa[4];
    #pragma unroll
    for (int j = 0; j < 4; ++j) pa[j] = (f32x4){0.f, 0.f, 0.f, 0.f};
    const us* wp = pzW + (size_t)(nt * 64 + srow) * 64 + scb;
    uint4 wv = *(const uint4*)wp;
    for (int k0 = 0; k0 < 64; k0 += 32) {
      __syncthreads();
      *(uint4*)&Bs[srow * 40 + scb] = wv;
      __syncthreads();
      if (k0 == 0) wv = *(const uint4*)(wp + 32);
      bf16x8 a = *(const bf16x8*)&zts[(w * 16 + l15) * 72 + k0 + q * 8];
      #pragma unroll
      for (int j = 0; j < 4; ++j) {
        bf16x8 b = *(const bf16x8*)&Bs[(j * 16 + l15) * 40 + q * 8];
        pa[j] = __builtin_amdgcn_mfma_f32_16x16x32_bf16(a, b, pa[j], 0, 0, 0);
      }
    }
    #pragma unroll
    for (int j = 0; j < 4; ++j) {
      const int col = nt * 64 + j * 16 + l15;
      const float bv = pzb[col];
      #pragma unroll
      for (int r = 0; r < 4; ++r) {
        const int row = m0 + w * 16 + q * 4 + r;
        phiz[(size_t)row * Hn + col] = f2b(fmaxf(pa[j][r] + bv, 0.f));
      }
    }
  }
  return kout;
}

// ================= the persistent mega-kernel (no nll) =================
__global__ __launch_bounds__(NTH, 1) void k_mega(KParams p)
{
  __shared__ alignas(16) char sm[20496];
  const int bid = blockIdx.x;
  const int gtid = bid * NTH + threadIdx.x;
  const int gnt = NB * NTH;
  int* bar = p.bar;

  // ---- stage 0: weight conversion + zero-init ----
  {
    const float* srcs[19] = {p.f_pxW2, p.f_pzW, p.f_pfW, p.f_rWih, p.f_rWhh,
        p.f_zpW, p.f_zpmW, p.f_zpsW, p.f_feWih, p.f_feWhh, p.f_femW, p.f_fesW,
        p.f_zeW1, p.f_zeW2, p.f_zemW, p.f_zesW, p.f_dW1, p.f_dW2, p.f_dmW};
    us* dsts[19] = {p.b_pxW2, p.b_pzW, p.b_pfW, p.b_rWih, p.b_rWhh,
        p.b_zpW, p.b_zpmW, p.b_zpsW, p.b_feWih, p.b_feWhh, p.b_femW, p.b_fesW,
        p.b_zeW1, p.b_zeW2, p.b_zemW, p.b_zesW, p.b_dW1, p.b_dW2, p.b_dmW};
    const int ns[19] = {512*512, 512*64, 512*64, 1536*1536, 1536*512,
        512*512, 64*512, 64*512, 1536*512, 1536*512, 64*512, 64*512,
        512*1024, 512*512, 64*512, 64*512, 512*1536, 512*512, 784*512};
    for (int k = 0; k < 19; ++k) {
      const float* s = srcs[k]; us* d = dsts[k]; const int n = ns[k];
      for (int i = gtid; i < n; i += gnt) d[i] = f2b(s[i]);
    }
  }
  for (int i = gtid; i < 512 * XnP; i += gnt) {
    const int r = i / XnP, c = i - r * XnP;
    p.b_pxW1[i] = (c < Xn) ? f2b(p.f_pxW1[(size_t)r * Xn + c]) : (us)0;
  }
  for (int i = gtid; i < Bn * Hn; i += gnt) { p.fh_a[i] = 0; p.h_a[i] = 0; }
  for (int i = gtid; i < Bn * 1536; i += gnt) p.ghpre[i] = 0.f;
  gsync(bar);

  // ---- Phase A: phi_x = relu(relu(x@pxW1^T+b)@pxW2^T+b), chunked ----
  const int CH = p.CH;
  const int nch = Tn / CH;
  for (int c = 0; c < nch; ++c) {
    const int nx = CH * Bn * XnP;
    const float* xsrc = p.x + (size_t)c * CH * Bn * Xn;
    for (int i = gtid; i < nx; i += gnt) {
      const int r = i / XnP, cc = i - r * XnP;
      p.xch[i] = (cc < Xn) ? f2b(xsrc[(size_t)r * Xn + cc]) : (us)0;
    }
    gsync(bar);
    const int ntile = (CH * Bn / 64) * 8;
    for (int tl = bid; tl < ntile; tl += NB)
      tile_gemmx<1, true, false, false, true>(tl & 7, tl >> 3, p.xch, p.b_pxW1,
          XnP, XnP, nullptr, nullptr, 0, 0, nullptr, 0, p.pxb1, p.tmpb, Hn, sm);
    gsync(bar);
    for (int tl = bid; tl < ntile; tl += NB)
      tile_gemmx<1, true, false, false, true>(tl & 7, tl >> 3, p.tmpb, p.b_pxW2,
          Hn, Hn, nullptr, nullptr, 0, 0, nullptr, 0, p.pxb2,
          p.phi_x + (size_t)c * CH * Bn * Hn, Hn, sm);
    gsync(bar);
  }

  // ---- Phase B: f-encoder GRU; gi pipelined one step ahead on idle blocks.
  // gi double buffer ALIASES Cpre_gru / gipre (unused until the prologue). ----
  float* giA = p.Cpre_gru;
  float* giB = p.gipre;
  if (bid < 64)
    tile_g3<false>(bid & 7, bid >> 3, p.phi_x, p.b_feWih, Hn, nullptr, giA, sm);
  gsync(bar);
  for (int t = 0; t < Tn; ++t) {
    const us* hc = (t & 1) ? p.fh_b : p.fh_a;
    us* hn = (t & 1) ? p.fh_a : p.fh_b;
    const float* gic = (t & 1) ? giB : giA;
    float* gin = (t & 1) ? giA : giB;
    if (bid < 64)
      tile_ghgates(bid & 7, bid >> 3, hc, p.b_feWhh, gic, p.febih, p.febhh, hn, sm);
    else if (bid < 128 && t + 1 < Tn)
      tile_g3<false>((bid - 64) & 7, (bid - 64) >> 3,
          p.phi_x + (size_t)(t + 1) * Bn * Hn, p.b_feWih, Hn, nullptr, gin, sm);
    gsync(bar);
  }

  // ---- Phase C: f stats + (independent) zepre0, zp0 ----
  if (bid < 8) {
    const float fk = stat_dual<1>(bid, p.fh_a, p.b_femW, p.femb, p.b_fesW, p.fesb,
                                  p.eps_f, p.fbuf, nullptr, nullptr, sm);
    if (threadIdx.x == 0) p.parts[8 + bid] = fk;
  } else if (bid < 72)
    tile_gemmx<1, true, false, false, true>((bid - 8) & 7, (bid - 8) >> 3,
        p.phi_x, p.b_zeW1, 1024, Hn, nullptr, nullptr, 0, 0,
        nullptr, 0, p.zeb1, p.zepre, Hn, sm);   // h0=0 => only px seg contributes
  else {
    // zp0[m][c] = relu(zpb[c])   (h0 = 0)
    for (int i = (bid - 72) * NTH + threadIdx.x; i < Bn * Hn; i += (NB - 72) * NTH)
      p.zp[i] = f2b(fmaxf(p.zpb[i & (Hn - 1)], 0.f));
  }
  gsync(bar);

  // ---- Prologue A: phi_f | ze0 | zpstat0 ----
  if (bid < 64)
    tile_gemmx<1, true, false, false, true>(bid & 7, bid >> 3, p.fbuf, p.b_pfW,
        Fn, Fn, nullptr, nullptr, 0, 0, nullptr, 0, p.pfb, p.phi_f, Hn, sm);
  else if (bid < 128)
    tile_gemmx<1, true, false, false, true>((bid - 64) & 7, (bid - 64) >> 3,
        p.zepre, p.b_zeW2, Hn, Hn, nullptr, nullptr, 0, 0,
        nullptr, 0, p.zeb2, p.ze, Hn, sm);
  else if (bid < 136)
    stat_dual<0>(bid - 128, p.zp, p.b_zpmW, p.zpmb, p.b_zpsW, p.zpsb, nullptr,
                 nullptr, p.zpm, p.zps, sm);
  gsync(bar);

  // ---- Prologue B: Cpre_gru | Cpre_dec  (overwrites the Phase-B gi aliases) ----
  if (bid < 64)
    tile_g3<false>(bid & 7, bid >> 3, p.phi_f, p.b_rWih + 1024, 1536,
                   nullptr, p.Cpre_gru, sm);
  else if (bid < 128)
    tile_gemmx<1, false, true, false, true>((bid - 64) & 7, (bid - 64) >> 3,
        p.phi_f, p.b_dW1 + 512, 1536, Hn, nullptr, nullptr, 0, 0,
        nullptr, 0, p.db1, p.Cpre_dec, 512, sm);
  gsync(bar);

  // ---- Phase D: 4 barriers per timestep.  dec(t) is written into the
  // phi_x[t] slot (dead after D1(t)); nll is computed by a separate ordinary
  // kernel after this one. ----
  float accZ = 0.f;
  for (int t = 0; t < Tn; ++t) {
    const us* hc = (t & 1) ? p.h_b : p.h_a;
    us* hn = (t & 1) ? p.h_a : p.h_b;
    const us* px_t = p.phi_x + (size_t)t * Bn * Hn;

    // D1: zestat+phiz (8) | gipre(t) (64)
    if (bid < 8)
      accZ += tile_zestat_phiz(bid, p.ze, p.b_zemW, p.zemb, p.b_zesW, p.zesb,
          p.eps_z + (size_t)t * Bn * Zn, p.zpm, p.zps,
          p.b_pzW, p.pzb, p.phiz, sm);
    else if (bid < 72)
      tile_g3<true>((bid - 8) & 7, (bid - 8) >> 3, px_t, p.b_rWih, 1536,
                    p.Cpre_gru, p.gipre, sm);
    gsync(bar);

    // D2: gru_fin (64) | dtmp (64)
    if (bid < 64)
      tile_gru_fin(bid & 7, bid >> 3, p.phiz, p.b_rWih, p.gipre, p.ghpre, hc,
                   p.rbih, p.rbhh, hn, sm);
    else if (bid < 128)
      tile_gemmx<1, true, false, true, false>((bid - 64) & 7, (bid - 64) >> 3,
          p.phiz, p.b_dW1, 1536, Hn, nullptr, nullptr, 0, 0,
          (t == 0 ? p.Cpre_dec : p.dtmph), 512, nullptr, p.dtmp, Hn, sm);
    gsync(bar);

    // D3: dec -> phi_x[t] slot (64) | zp' (64) | zepre' (64) | dtmph' (64)
    if (bid < 64)
      tile_gemmx<1, true, false, false, true>(bid & 7, bid >> 3, p.dtmp, p.b_dW2,
          Hn, Hn, nullptr, nullptr, 0, 0, nullptr, 0, p.db2,
          p.phi_x + (size_t)t * Bn * Hn, Hn, sm);
    else if (bid < 128) {
      if (t + 1 < Tn)
        tile_gemmx<1, true, false, false, true>((bid - 64) & 7, (bid - 64) >> 3,
            hn, p.b_zpW, Hn, Hn, nullptr, nullptr, 0, 0,
            nullptr, 0, p.zpb, p.zp, Hn, sm);
    } else if (bid < 192) {
      if (t + 1 < Tn)
        tile_gemmx<2, true, false, false, true>((bid - 128) & 7, (bid - 128) >> 3,
            p.phi_x + (size_t)(t + 1) * Bn * Hn, p.b_zeW1, 1024, Hn,
            hn, p.b_zeW1 + 512, 1024, Hn,
            nullptr, 0, p.zeb1, p.zepre, Hn, sm);
    } else {
      if (t + 1 < Tn)
        tile_gemmx<1, false, true, true, false>((bid - 192) & 7, (bid - 192) >> 3,
            hn, p.b_dW1 + 1024, 1536, Hn, nullptr, nullptr, 0, 0,
            p.Cpre_dec, 512, nullptr, p.dtmph, 512, sm);
    }
    gsync(bar);

    // D4: ze' (64) | zpstat' (8) | ghpre' (64)
    if (t + 1 < Tn) {
      if (bid < 64)
        tile_gemmx<1, true, false, false, true>(bid & 7, bid >> 3, p.zepre,
            p.b_zeW2, Hn, Hn, nullptr, nullptr, 0, 0,
            nullptr, 0, p.zeb2, p.ze, Hn, sm);
      else if (bid < 72)
        stat_dual<0>(bid - 64, p.zp, p.b_zpmW, p.zpmb, p.b_zpsW, p.zpsb, nullptr,
                     nullptr, p.zpm, p.zps, sm);
      else if (bid < 136)
        tile_g3<false>((bid - 72) & 7, (bid - 72) >> 3, hn, p.b_rWhh, Hn,
                       nullptr, p.ghpre, sm);
    }
    gsync(bar);
  }

  // ---- finalize f_kld / z_kld (out[2] comes from the nll kernel) ----
  if (threadIdx.x == 0 && bid < 8) p.parts[bid] = accZ;
  gsync(bar);
  if (bid == 0 && threadIdx.x == 0) {
    float f = 0.f, z = 0.f;
    for (int i = 0; i < 8; ++i) { z += p.parts[i]; f += p.parts[8 + i]; }
    p.out[0] = f; p.out[1] = z;
  }
}

// ================= ordinary nll kernel (round-0-proven mechanism) =================
// grid = 64*104 blocks; block b: t = b/104, tile i = b%104 (13 x-tiles, 8 b-tiles)
__global__ __launch_bounds__(NTH) void k_nll_all(
    const us* dec_all, const us* dmW, const float* dmb, const float* x, float* nll)
{
  __shared__ alignas(16) char smemc[10256];
  const int b = blockIdx.x;
  const int t = b / 104;
  const int i = b - t * 104;
  const int bx = i % 13, by = i / 13;
  const us* dec = dec_all + (size_t)t * Bn * Hn;
  const float* xt = x + (size_t)t * Bn * Xn;

  us* As = (us*)smemc; us* Bs = (us*)(smemc + 5120);
  float* red = (float*)(smemc + 10240);
  const int tid = threadIdx.x, srow = tid >> 2, scb = (tid & 3) * 8;
  const int lane = tid & 63, w = tid >> 6, l15 = lane & 15, q = lane >> 4;
  const int m0 = by * 64, n0 = bx * 64;
  f32x4 acc[4];
  #pragma unroll
  for (int j = 0; j < 4; ++j) acc[j] = (f32x4){0.f, 0.f, 0.f, 0.f};
  const int wrow = (n0 + srow < Xn) ? (n0 + srow) : (Xn - 1);
  const us* ap = dec + (size_t)(m0 + srow) * Hn + scb;
  const us* wp = dmW + (size_t)wrow * Hn + scb;
  uint4 av = *(const uint4*)ap;
  uint4 wv = *(const uint4*)wp;
  for (int k0 = 0; k0 < Hn; k0 += 32) {
    __syncthreads();
    *(uint4*)&As[srow * 40 + scb] = av;
    *(uint4*)&Bs[srow * 40 + scb] = wv;
    __syncthreads();
    if (k0 + 32 < Hn) {
      av = *(const uint4*)(ap + k0 + 32);
      wv = *(const uint4*)(wp + k0 + 32);
    }
    bf16x8 a = *(const bf16x8*)&As[(w * 16 + l15) * 40 + q * 8];
    #pragma unroll
    for (int j = 0; j < 4; ++j) {
      bf16x8 bb = *(const bf16x8*)&Bs[(j * 16 + l15) * 40 + q * 8];
      acc[j] = __builtin_amdgcn_mfma_f32_16x16x32_bf16(a, bb, acc[j], 0, 0, 0);
    }
  }
  float sum = 0.0f;
  #pragma unroll
  for (int j = 0; j < 4; ++j) {
    const int n = n0 + j * 16 + l15;
    if (n < Xn) {
      const float bv = dmb[n];
      #pragma unroll
      for (int r = 0; r < 4; ++r) {
        const int m = m0 + w * 16 + q * 4 + r;
        const float a = acc[j][r] + bv;
        const float xv = xt[(size_t)m * Xn + n];
        sum += splusf(-a) + (1.0f - xv) * a;
      }
    }
  }
  const float s = block_sum(sum, red);
  if (tid == 0) atomicAdd(nll, s);
}

} // anonymous namespace

extern "C" void kernel_launch(void* const* d_in, const int* in_sizes, int n_in,
                              void* d_out, int out_size, void* d_ws, size_t ws_size,
                              hipStream_t stream)
{
  (void)in_sizes; (void)n_in; (void)out_size;
  KParams p;
  p.x      = (const float*)d_in[0];
  p.eps_f  = (const float*)d_in[1];
  p.eps_z  = (const float*)d_in[2];
  p.f_pxW1 = (const float*)d_in[3];
  p.pxb1   = (const float*)d_in[4];
  p.f_pxW2 = (const float*)d_in[5];
  p.pxb2   = (const float*)d_in[6];
  p.f_pzW  = (const float*)d_in[7];
  p.pzb    = (const float*)d_in[8];
  p.f_pfW  = (const float*)d_in[9];
  p.pfb    = (const float*)d_in[10];
  p.f_rWih = (const float*)d_in[11];
  p.f_rWhh = (const float*)d_in[12];
  p.rbih   = (const float*)d_in[13];
  p.rbhh   = (const float*)d_in[14];
  p.f_zpW  = (const float*)d_in[15];
  p.zpb    = (const float*)d_in[16];
  p.f_zpmW = (const float*)d_in[17];
  p.zpmb   = (const float*)d_in[18];
  p.f_zpsW = (const float*)d_in[19];
  p.zpsb   = (const float*)d_in[20];
  p.f_feWih = (const float*)d_in[21];
  p.f_feWhh = (const float*)d_in[22];
  p.febih  = (const float*)d_in[23];
  p.febhh  = (const float*)d_in[24];
  p.f_femW = (const float*)d_in[25];
  p.femb   = (const float*)d_in[26];
  p.f_fesW = (const float*)d_in[27];
  p.fesb   = (const float*)d_in[28];
  p.f_zeW1 = (const float*)d_in[29];
  p.zeb1   = (const float*)d_in[30];
  p.f_zeW2 = (const float*)d_in[31];
  p.zeb2   = (const float*)d_in[32];
  p.f_zemW = (const float*)d_in[33];
  p.zemb   = (const float*)d_in[34];
  p.f_zesW = (const float*)d_in[35];
  p.zesb   = (const float*)d_in[36];
  p.f_dW1  = (const float*)d_in[37];
  p.db1    = (const float*)d_in[38];
  p.f_dW2  = (const float*)d_in[39];
  p.db2    = (const float*)d_in[40];
  p.f_dmW  = (const float*)d_in[41];
  p.dmb    = (const float*)d_in[42];
  p.out    = (float*)d_out;

  char* base = (char*)d_ws;
  size_t off = 0;
  auto ab = [&](size_t bytes) -> void* {
    void* q = base + off;
    off += (bytes + 255) & ~(size_t)255;
    return q;
  };

  // bf16 weights
  p.b_pxW1  = (us*)ab((size_t)512 * XnP * 2);
  p.b_pxW2  = (us*)ab((size_t)512 * 512 * 2);
  p.b_pzW   = (us*)ab((size_t)512 * 64 * 2);
  p.b_pfW   = (us*)ab((size_t)512 * 64 * 2);
  p.b_rWih  = (us*)ab((size_t)1536 * 1536 * 2);
  p.b_rWhh  = (us*)ab((size_t)1536 * 512 * 2);
  p.b_zpW   = (us*)ab((size_t)512 * 512 * 2);
  p.b_zpmW  = (us*)ab((size_t)64 * 512 * 2);
  p.b_zpsW  = (us*)ab((size_t)64 * 512 * 2);
  p.b_feWih = (us*)ab((size_t)1536 * 512 * 2);
  p.b_feWhh = (us*)ab((size_t)1536 * 512 * 2);
  p.b_femW  = (us*)ab((size_t)64 * 512 * 2);
  p.b_fesW  = (us*)ab((size_t)64 * 512 * 2);
  p.b_zeW1  = (us*)ab((size_t)512 * 1024 * 2);
  p.b_zeW2  = (us*)ab((size_t)512 * 512 * 2);
  p.b_zemW  = (us*)ab((size_t)64 * 512 * 2);
  p.b_zesW  = (us*)ab((size_t)64 * 512 * 2);
  p.b_dW1   = (us*)ab((size_t)512 * 1536 * 2);
  p.b_dW2   = (us*)ab((size_t)512 * 512 * 2);
  p.b_dmW   = (us*)ab((size_t)Xn * 512 * 2);

  // activations
  p.phi_x = (us*)ab((size_t)Tn * Bn * Hn * 2);   // doubles as dec_all in Phase D
  p.fh_a  = (us*)ab((size_t)Bn * Hn * 2);
  p.fh_b  = (us*)ab((size_t)Bn * Hn * 2);
  p.h_a   = (us*)ab((size_t)Bn * Hn * 2);
  p.h_b   = (us*)ab((size_t)Bn * Hn * 2);
  p.fbuf  = (us*)ab((size_t)Bn * Fn * 2);
  p.phi_f = (us*)ab((size_t)Bn * Hn * 2);
  p.zp    = (us*)ab((size_t)Bn * Hn * 2);
  p.zepre = (us*)ab((size_t)Bn * Hn * 2);
  p.ze    = (us*)ab((size_t)Bn * Hn * 2);
  p.phiz  = (us*)ab((size_t)Bn * Hn * 2);
  p.dtmp  = (us*)ab((size_t)Bn * Hn * 2);
  p.dec   = (us*)ab((size_t)Bn * Hn * 2);
  p.zpm = (float*)ab((size_t)Bn * Zn * 4);
  p.zps = (float*)ab((size_t)Bn * Zn * 4);
  p.Cpre_gru = (float*)ab((size_t)Bn * 1536 * 4);
  p.Cpre_dec = (float*)ab((size_t)Bn * 512 * 4);
  p.gipre    = (float*)ab((size_t)Bn * 1536 * 4);
  p.ghpre    = (float*)ab((size_t)Bn * 1536 * 4);
  p.dtmph    = (float*)ab((size_t)Bn * 512 * 4);
  p.parts    = (float*)ab((size_t)16 * 4);
  p.bar      = (int*)ab((size_t)256);

  int CH = 16;
  while (CH > 1 && off + (size_t)CH * (Bn * XnP + Bn * Hn) * 2 + 4096 > ws_size) CH >>= 1;
  p.xch  = (us*)ab((size_t)CH * Bn * XnP * 2);
  p.tmpb = (us*)ab((size_t)CH * Bn * Hn * 2);
  p.CH = CH;

  // reset barrier state for this run (captured per-launch under graph capture)
  hipMemsetAsync(p.bar, 0, 256, stream);

  void* args[] = { (void*)&p };
  hipLaunchCooperativeKernel((const void*)k_mega, dim3(NB), dim3(NTH), args, 0, stream);

  // out[2] (nll): ordinary launch, atomicAdd into the harness-zeroed out buffer.
  k_nll_all<<<dim3(Tn * 104), dim3(NTH), 0, stream>>>(
      p.phi_x, p.b_dmW, p.dmb, p.x, p.out + 2);
}

// Round 8
// 6963.296 us; speedup vs baseline: 4.5849x; 4.5849x over previous
//
#include <hip/hip_runtime.h>
#include <cmath>

namespace {

constexpr int Tn = 64;
constexpr int Bn = 512;
constexpr int Xn = 784;
constexpr int XnP = 800;
constexpr int Fn = 64;
constexpr int Zn = 64;
constexpr int Hn = 512;

typedef unsigned short us;
typedef __attribute__((ext_vector_type(8))) short bf16x8;
typedef __attribute__((ext_vector_type(4))) float f32x4;

__device__ __forceinline__ us f2b(float v) {
  unsigned int u = __float_as_uint(v);
  return (us)((u + 0x7FFFu + ((u >> 16) & 1u)) >> 16);
}
__device__ __forceinline__ float b2f(us u) { return __uint_as_float(((unsigned int)u) << 16); }
__device__ __forceinline__ float sigmf(float v) { return 1.0f / (1.0f + __expf(-v)); }
__device__ __forceinline__ float splusf(float v) {
  return v > 0.0f ? (v + log1pf(__expf(-v))) : log1pf(__expf(v));
}
__device__ __forceinline__ float block_sum(float v, float* red) {
  #pragma unroll
  for (int off = 32; off > 0; off >>= 1) v += __shfl_down(v, off, 64);
  if ((threadIdx.x & 63) == 0) red[threadIdx.x >> 6] = v;
  __syncthreads();
  float s = 0.0f;
  if (threadIdx.x == 0) s = red[0] + red[1] + red[2] + red[3];
  return s;
}

// ---- fused weight converter ----
struct CvtP {
  const float* s[19];
  us* d[19];
  int n[19];
  const float* pxW1src;
  us* pxW1dst;
};
__global__ __launch_bounds__(256) void k_cvt_all(CvtP p) {
  const int gtid = blockIdx.x * 256 + threadIdx.x;
  const int gnt = gridDim.x * 256;
  for (int k = 0; k < 19; ++k) {
    const float* s = p.s[k]; us* d = p.d[k]; const int n = p.n[k];
    for (int i = gtid; i < n; i += gnt) d[i] = f2b(s[i]);
  }
  for (int i = gtid; i < 512 * XnP; i += gnt) {
    const int r = i / XnP, c = i - r * XnP;
    p.pxW1dst[i] = (c < Xn) ? f2b(p.pxW1src[(size_t)r * Xn + c]) : (us)0;
  }
}

__global__ __launch_bounds__(256) void cvt_pad(
    const float* __restrict__ s, us* __restrict__ d, int C, int Cp, int n) {
  int i = blockIdx.x * 256 + threadIdx.x;
  if (i < n) {
    int r = i / Cp, c = i - r * Cp;
    d[i] = (c < C) ? f2b(s[(size_t)r * C + c]) : (us)0;
  }
}

// ================= tile device functions =================
// 64x64 GEMM tile with optional fp32 accumulator init, fp32/bf16 out, bias, relu.
// smem >= 10240 B.
template <int NSEG, bool RELU, bool F32OUT, bool HASINIT, bool HASBIAS>
__device__ void tile_gemmx(
    int bx, int by,
    const us* A0, const us* W0, int ldw0, int K0,
    const us* A1, const us* W1, int ldw1, int K1,
    const float* initC, int ldi, const float* bias,
    void* Cout, int ldc, char* smemc)
{
  us* As = (us*)smemc; us* Bs = (us*)(smemc + 5120);
  const int tid = threadIdx.x, srow = tid >> 2, scb = (tid & 3) * 8;
  const int lane = tid & 63, w = tid >> 6, l15 = lane & 15, q = lane >> 4;
  const int m0 = by * 64, n0 = bx * 64;
  f32x4 acc[4];
  if (HASINIT) {
    #pragma unroll
    for (int j = 0; j < 4; ++j)
      #pragma unroll
      for (int r = 0; r < 4; ++r)
        acc[j][r] = initC[(size_t)(m0 + w * 16 + q * 4 + r) * ldi + n0 + j * 16 + l15];
  } else {
    #pragma unroll
    for (int j = 0; j < 4; ++j) acc[j] = (f32x4){0.f, 0.f, 0.f, 0.f};
  }
  #pragma unroll
  for (int seg = 0; seg < NSEG; ++seg) {
    const us* A = (seg == 0) ? A0 : A1;
    const us* W = (seg == 0) ? W0 : W1;
    const int ldw = (seg == 0) ? ldw0 : ldw1;
    const int K   = (seg == 0) ? K0 : K1;
    const us* ap = A + (size_t)(m0 + srow) * K + scb;
    const us* wp = W + (size_t)(n0 + srow) * ldw + scb;
    uint4 av = *(const uint4*)ap;
    uint4 wv = *(const uint4*)wp;
    for (int k0 = 0; k0 < K; k0 += 32) {
      __syncthreads();
      *(uint4*)&As[srow * 40 + scb] = av;
      *(uint4*)&Bs[srow * 40 + scb] = wv;
      __syncthreads();
      if (k0 + 32 < K) {
        av = *(const uint4*)(ap + k0 + 32);
        wv = *(const uint4*)(wp + k0 + 32);
      }
      bf16x8 a = *(const bf16x8*)&As[(w * 16 + l15) * 40 + q * 8];
      #pragma unroll
      for (int j = 0; j < 4; ++j) {
        bf16x8 b = *(const bf16x8*)&Bs[(j * 16 + l15) * 40 + q * 8];
        acc[j] = __builtin_amdgcn_mfma_f32_16x16x32_bf16(a, b, acc[j], 0, 0, 0);
      }
    }
  }
  #pragma unroll
  for (int j = 0; j < 4; ++j) {
    const int col = n0 + j * 16 + l15;
    const float bv = HASBIAS ? bias[col] : 0.f;
    #pragma unroll
    for (int r = 0; r < 4; ++r) {
      const int row = m0 + w * 16 + q * 4 + r;
      float v = acc[j][r] + bv;
      if (RELU) v = fmaxf(v, 0.f);
      if (F32OUT) ((float*)Cout)[(size_t)row * ldc + col] = v;
      else        ((us*)Cout)[(size_t)row * ldc + col] = f2b(v);
    }
  }
}

// 3-gate GEMM: out[row][{c,512+c,1024+c}] (+= init) = A @ Wgate^T, K=Hn.
// out is fp32 [Bn][1536]. smem >= 20480 B.
template <bool HASINIT>
__device__ void tile_g3(int bx, int by, const us* A, const us* W, int ldw,
                        const float* initC, float* outC, char* smemc)
{
  us* Asm = (us*)smemc; us* Rs = (us*)(smemc + 5120);
  us* Zs = (us*)(smemc + 10240); us* Ns = (us*)(smemc + 15360);
  const int tid = threadIdx.x, srow = tid >> 2, scb = (tid & 3) * 8;
  const int lane = tid & 63, w = tid >> 6, l15 = lane & 15, q = lane >> 4;
  const int m0 = by * 64, c0 = bx * 64;
  f32x4 aR[4], aZ[4], aN[4];
  if (HASINIT) {
    #pragma unroll
    for (int j = 0; j < 4; ++j) {
      const int c = c0 + j * 16 + l15;
      #pragma unroll
      for (int r = 0; r < 4; ++r) {
        const size_t row = (size_t)(m0 + w * 16 + q * 4 + r) * 1536;
        aR[j][r] = initC[row + c];
        aZ[j][r] = initC[row + 512 + c];
        aN[j][r] = initC[row + 1024 + c];
      }
    }
  } else {
    #pragma unroll
    for (int j = 0; j < 4; ++j) {
      aR[j] = (f32x4){0.f, 0.f, 0.f, 0.f}; aZ[j] = aR[j]; aN[j] = aR[j];
    }
  }
  const us* ap = A + (size_t)(m0 + srow) * Hn + scb;
  const us* wr = W + (size_t)(c0 + srow) * ldw + scb;
  const us* wz = wr + (size_t)512 * ldw;
  const us* wn = wz + (size_t)512 * ldw;
  uint4 av = *(const uint4*)ap;
  uint4 rv = *(const uint4*)wr;
  uint4 zv = *(const uint4*)wz;
  uint4 nv = *(const uint4*)wn;
  for (int k0 = 0; k0 < Hn; k0 += 32) {
    __syncthreads();
    *(uint4*)&Asm[srow * 40 + scb] = av;
    *(uint4*)&Rs[srow * 40 + scb] = rv;
    *(uint4*)&Zs[srow * 40 + scb] = zv;
    *(uint4*)&Ns[srow * 40 + scb] = nv;
    __syncthreads();
    if (k0 + 32 < Hn) {
      av = *(const uint4*)(ap + k0 + 32);
      rv = *(const uint4*)(wr + k0 + 32);
      zv = *(const uint4*)(wz + k0 + 32);
      nv = *(const uint4*)(wn + k0 + 32);
    }
    bf16x8 a = *(const bf16x8*)&Asm[(w * 16 + l15) * 40 + q * 8];
    #pragma unroll
    for (int j = 0; j < 4; ++j) {
      bf16x8 br = *(const bf16x8*)&Rs[(j * 16 + l15) * 40 + q * 8];
      bf16x8 bz = *(const bf16x8*)&Zs[(j * 16 + l15) * 40 + q * 8];
      bf16x8 bn = *(const bf16x8*)&Ns[(j * 16 + l15) * 40 + q * 8];
      aR[j] = __builtin_amdgcn_mfma_f32_16x16x32_bf16(a, br, aR[j], 0, 0, 0);
      aZ[j] = __builtin_amdgcn_mfma_f32_16x16x32_bf16(a, bz, aZ[j], 0, 0, 0);
      aN[j] = __builtin_amdgcn_mfma_f32_16x16x32_bf16(a, bn, aN[j], 0, 0, 0);
    }
  }
  #pragma unroll
  for (int j = 0; j < 4; ++j) {
    const int c = c0 + j * 16 + l15;
    #pragma unroll
    for (int r = 0; r < 4; ++r) {
      const size_t row = (size_t)(m0 + w * 16 + q * 4 + r) * 1536;
      outC[row + c] = aR[j][r];
      outC[row + 512 + c] = aZ[j][r];
      outC[row + 1024 + c] = aN[j][r];
    }
  }
}

// Phase-B GRU tile (2 segs: gi = A0@Wih^T, gh = h@Whh^T). smem >= 20480 B.
__device__ void tile_gru_fe(
    int bx, int by,
    const us* A0, const us* Wih,
    const us* hprev, const us* Whh,
    const float* bih, const float* bhh,
    us* hnew, char* smemc)
{
  us* Asm = (us*)smemc; us* Rs = (us*)(smemc + 5120);
  us* Zs = (us*)(smemc + 10240); us* Ns = (us*)(smemc + 15360);
  const int tid = threadIdx.x, srow = tid >> 2, scb = (tid & 3) * 8;
  const int lane = tid & 63, w = tid >> 6, l15 = lane & 15, q = lane >> 4;
  const int m0 = by * 64, c0 = bx * 64;
  f32x4 aR[4], aZ[4], aI[4], aH[4];
  #pragma unroll
  for (int j = 0; j < 4; ++j) {
    aR[j] = (f32x4){0.f, 0.f, 0.f, 0.f}; aZ[j] = aR[j]; aI[j] = aR[j]; aH[j] = aR[j];
  }
  #pragma unroll
  for (int seg = 0; seg < 2; ++seg) {
    const bool hseg = (seg == 1);
    const us* A  = hseg ? hprev : A0;
    const us* Wb = hseg ? Whh : Wih;
    const us* ap = A + (size_t)(m0 + srow) * Hn + scb;
    const us* wr = Wb + (size_t)(c0 + srow) * Hn + scb;
    const us* wz = wr + (size_t)Hn * Hn;
    const us* wn = wz + (size_t)Hn * Hn;
    uint4 av = *(const uint4*)ap;
    uint4 rv = *(const uint4*)wr;
    uint4 zv = *(const uint4*)wz;
    uint4 nv = *(const uint4*)wn;
    for (int k0 = 0; k0 < Hn; k0 += 32) {
      __syncthreads();
      *(uint4*)&Asm[srow * 40 + scb] = av;
      *(uint4*)&Rs[srow * 40 + scb] = rv;
      *(uint4*)&Zs[srow * 40 + scb] = zv;
      *(uint4*)&Ns[srow * 40 + scb] = nv;
      __syncthreads();
      if (k0 + 32 < Hn) {
        av = *(const uint4*)(ap + k0 + 32);
        rv = *(const uint4*)(wr + k0 + 32);
        zv = *(const uint4*)(wz + k0 + 32);
        nv = *(const uint4*)(wn + k0 + 32);
      }
      bf16x8 a = *(const bf16x8*)&Asm[(w * 16 + l15) * 40 + q * 8];
      #pragma unroll
      for (int j = 0; j < 4; ++j) {
        bf16x8 br = *(const bf16x8*)&Rs[(j * 16 + l15) * 40 + q * 8];
        bf16x8 bz = *(const bf16x8*)&Zs[(j * 16 + l15) * 40 + q * 8];
        bf16x8 bn = *(const bf16x8*)&Ns[(j * 16 + l15) * 40 + q * 8];
        aR[j] = __builtin_amdgcn_mfma_f32_16x16x32_bf16(a, br, aR[j], 0, 0, 0);
        aZ[j] = __builtin_amdgcn_mfma_f32_16x16x32_bf16(a, bz, aZ[j], 0, 0, 0);
        if (hseg) aH[j] = __builtin_amdgcn_mfma_f32_16x16x32_bf16(a, bn, aH[j], 0, 0, 0);
        else      aI[j] = __builtin_amdgcn_mfma_f32_16x16x32_bf16(a, bn, aI[j], 0, 0, 0);
      }
    }
  }
  #pragma unroll
  for (int j = 0; j < 4; ++j) {
    const int c = c0 + j * 16 + l15;
    const float bR = bih[c] + bhh[c];
    const float bZ = bih[Hn + c] + bhh[Hn + c];
    const float bI = bih[2 * Hn + c];
    const float bH = bhh[2 * Hn + c];
    #pragma unroll
    for (int r = 0; r < 4; ++r) {
      const int m = m0 + w * 16 + q * 4 + r;
      const float h = b2f(hprev[(size_t)m * Hn + c]);
      const float rg = sigmf(aR[j][r] + bR);
      const float zg = sigmf(aZ[j][r] + bZ);
      const float ng = tanhf(aI[j][r] + bI + rg * (aH[j][r] + bH));
      hnew[(size_t)m * Hn + c] = f2b((1.0f - zg) * ng + zg * h);
    }
  }
}

// Phase-D GRU final tile.
__device__ void tile_gru_fin(
    int bx, int by,
    const us* phiz, const us* rWih,
    const float* gipre, const float* ghpre,
    const us* hprev,
    const float* bih, const float* bhh,
    us* hnew, char* smemc)
{
  us* Asm = (us*)smemc; us* Rs = (us*)(smemc + 5120);
  us* Zs = (us*)(smemc + 10240); us* Ns = (us*)(smemc + 15360);
  const int tid = threadIdx.x, srow = tid >> 2, scb = (tid & 3) * 8;
  const int lane = tid & 63, w = tid >> 6, l15 = lane & 15, q = lane >> 4;
  const int m0 = by * 64, c0 = bx * 64;
  f32x4 aR[4], aZ[4], aI[4];
  float aH[4][4];
  #pragma unroll
  for (int j = 0; j < 4; ++j) {
    const int c = c0 + j * 16 + l15;
    #pragma unroll
    for (int r = 0; r < 4; ++r) {
      const size_t row = (size_t)(m0 + w * 16 + q * 4 + r) * 1536;
      aR[j][r] = gipre[row + c] + ghpre[row + c];
      aZ[j][r] = gipre[row + 512 + c] + ghpre[row + 512 + c];
      aI[j][r] = gipre[row + 1024 + c];
      aH[j][r] = ghpre[row + 1024 + c];
    }
  }
  const us* ap = phiz + (size_t)(m0 + srow) * Hn + scb;
  const us* wr = rWih + (size_t)(c0 + srow) * 1536 + 512 + scb;
  const us* wz = wr + (size_t)512 * 1536;
  const us* wn = wz + (size_t)512 * 1536;
  uint4 av = *(const uint4*)ap;
  uint4 rv = *(const uint4*)wr;
  uint4 zv = *(const uint4*)wz;
  uint4 nv = *(const uint4*)wn;
  for (int k0 = 0; k0 < Hn; k0 += 32) {
    __syncthreads();
    *(uint4*)&Asm[srow * 40 + scb] = av;
    *(uint4*)&Rs[srow * 40 + scb] = rv;
    *(uint4*)&Zs[srow * 40 + scb] = zv;
    *(uint4*)&Ns[srow * 40 + scb] = nv;
    __syncthreads();
    if (k0 + 32 < Hn) {
      av = *(const uint4*)(ap + k0 + 32);
      rv = *(const uint4*)(wr + k0 + 32);
      zv = *(const uint4*)(wz + k0 + 32);
      nv = *(const uint4*)(wn + k0 + 32);
    }
    bf16x8 a = *(const bf16x8*)&Asm[(w * 16 + l15) * 40 + q * 8];
    #pragma unroll
    for (int j = 0; j < 4; ++j) {
      bf16x8 br = *(const bf16x8*)&Rs[(j * 16 + l15) * 40 + q * 8];
      bf16x8 bz = *(const bf16x8*)&Zs[(j * 16 + l15) * 40 + q * 8];
      bf16x8 bn = *(const bf16x8*)&Ns[(j * 16 + l15) * 40 + q * 8];
      aR[j] = __builtin_amdgcn_mfma_f32_16x16x32_bf16(a, br, aR[j], 0, 0, 0);
      aZ[j] = __builtin_amdgcn_mfma_f32_16x16x32_bf16(a, bz, aZ[j], 0, 0, 0);
      aI[j] = __builtin_amdgcn_mfma_f32_16x16x32_bf16(a, bn, aI[j], 0, 0, 0);
    }
  }
  #pragma unroll
  for (int j = 0; j < 4; ++j) {
    const int c = c0 + j * 16 + l15;
    const float bR = bih[c] + bhh[c];
    const float bZ = bih[Hn + c] + bhh[Hn + c];
    const float bI = bih[2 * Hn + c];
    const float bH = bhh[2 * Hn + c];
    #pragma unroll
    for (int r = 0; r < 4; ++r) {
      const int m = m0 + w * 16 + q * 4 + r;
      const float h = b2f(hprev[(size_t)m * Hn + c]);
      const float rg = sigmf(aR[j][r] + bR);
      const float zg = sigmf(aZ[j][r] + bZ);
      const float ng = tanhf(aI[j][r] + bI + rg * (aH[j][r] + bH));
      hnew[(size_t)m * Hn + c] = f2b((1.0f - zg) * ng + zg * h);
    }
  }
}

// dual-head stats tile, MODE 0 (prior heads -> fp32) / MODE 1 (f stats + kld).
// smem >= 15376 B.
template <int MODE>
__device__ void stat_dual(int vb,
    const us* Ain, const us* Wm, const float* bm, const us* Ws, const float* bs,
    const float* eps,
    us* o0b, float* o_pm, float* o_ps, float* kacc, char* smemc)
{
  us* As = (us*)smemc; us* Ms = (us*)(smemc + 5120); us* Ss = (us*)(smemc + 10240);
  float* red = (float*)(smemc + 15360);
  const int tid = threadIdx.x, srow = tid >> 2, scb = (tid & 3) * 8;
  const int lane = tid & 63, w = tid >> 6, l15 = lane & 15, q = lane >> 4;
  const int m0 = vb * 64;
  f32x4 am[4], as_[4];
  #pragma unroll
  for (int j = 0; j < 4; ++j) { am[j] = (f32x4){0.f, 0.f, 0.f, 0.f}; as_[j] = am[j]; }
  const us* ap = Ain + (size_t)(m0 + srow) * Hn + scb;
  const us* mp = Wm + (size_t)srow * Hn + scb;
  const us* sp = Ws + (size_t)srow * Hn + scb;
  uint4 av = *(const uint4*)ap;
  uint4 mv = *(const uint4*)mp;
  uint4 sv = *(const uint4*)sp;
  for (int k0 = 0; k0 < Hn; k0 += 32) {
    __syncthreads();
    *(uint4*)&As[srow * 40 + scb] = av;
    *(uint4*)&Ms[srow * 40 + scb] = mv;
    *(uint4*)&Ss[srow * 40 + scb] = sv;
    __syncthreads();
    if (k0 + 32 < Hn) {
      av = *(const uint4*)(ap + k0 + 32);
      mv = *(const uint4*)(mp + k0 + 32);
      sv = *(const uint4*)(sp + k0 + 32);
    }
    bf16x8 a = *(const bf16x8*)&As[(w * 16 + l15) * 40 + q * 8];
    #pragma unroll
    for (int j = 0; j < 4; ++j) {
      bf16x8 b0 = *(const bf16x8*)&Ms[(j * 16 + l15) * 40 + q * 8];
      bf16x8 b1 = *(const bf16x8*)&Ss[(j * 16 + l15) * 40 + q * 8];
      am[j]  = __builtin_amdgcn_mfma_f32_16x16x32_bf16(a, b0, am[j], 0, 0, 0);
      as_[j] = __builtin_amdgcn_mfma_f32_16x16x32_bf16(a, b1, as_[j], 0, 0, 0);
    }
  }
  float kld = 0.0f;
  #pragma unroll
  for (int j = 0; j < 4; ++j) {
    const int c = j * 16 + l15;
    const float bmv = bm[c], bsv = bs[c];
    #pragma unroll
    for (int r = 0; r < 4; ++r) {
      const int m = m0 + w * 16 + q * 4 + r;
      const float mu = am[j][r] + bmv;
      const float sd = splusf(as_[j][r] + bsv);
      if (MODE == 0) {
        o_pm[(size_t)m * Zn + c] = mu;
        o_ps[(size_t)m * Zn + c] = sd;
      } else {
        o0b[(size_t)m * Zn + c] = f2b(eps[(size_t)m * Zn + c] * sd + mu);
        kld += mu * mu + sd * sd - 2.0f * __logf(sd) - 1.0f;
      }
    }
  }
  if (MODE != 0) {
    const float s = block_sum(kld, red);
    if (tid == 0) atomicAdd(kacc, 0.5f * s);
  }
}

// zestat (prior-KLD) fused with phiz = relu(zt @ pzW^T + pzb); zt stays in LDS.
// smem >= 20480 B.
__device__ void tile_zestat_phiz(int vb,
    const us* ze, const us* Wm, const float* bm, const us* Ws, const float* bs,
    const float* eps, const float* pm_in, const float* ps_in,
    const us* pzW, const float* pzb, us* phiz,
    float* kacc, char* smemc)
{
  us* As = (us*)smemc; us* Ms = (us*)(smemc + 5120); us* Ss = (us*)(smemc + 10240);
  float* red = (float*)(smemc + 15360);
  const int tid = threadIdx.x, srow = tid >> 2, scb = (tid & 3) * 8;
  const int lane = tid & 63, w = tid >> 6, l15 = lane & 15, q = lane >> 4;
  const int m0 = vb * 64;
  f32x4 am[4], as_[4];
  #pragma unroll
  for (int j = 0; j < 4; ++j) { am[j] = (f32x4){0.f, 0.f, 0.f, 0.f}; as_[j] = am[j]; }
  const us* ap = ze + (size_t)(m0 + srow) * Hn + scb;
  const us* mp = Wm + (size_t)srow * Hn + scb;
  const us* sp = Ws + (size_t)srow * Hn + scb;
  uint4 av = *(const uint4*)ap;
  uint4 mv = *(const uint4*)mp;
  uint4 sv = *(const uint4*)sp;
  for (int k0 = 0; k0 < Hn; k0 += 32) {
    __syncthreads();
    *(uint4*)&As[srow * 40 + scb] = av;
    *(uint4*)&Ms[srow * 40 + scb] = mv;
    *(uint4*)&Ss[srow * 40 + scb] = sv;
    __syncthreads();
    if (k0 + 32 < Hn) {
      av = *(const uint4*)(ap + k0 + 32);
      mv = *(const uint4*)(mp + k0 + 32);
      sv = *(const uint4*)(sp + k0 + 32);
    }
    bf16x8 a = *(const bf16x8*)&As[(w * 16 + l15) * 40 + q * 8];
    #pragma unroll
    for (int j = 0; j < 4; ++j) {
      bf16x8 b0 = *(const bf16x8*)&Ms[(j * 16 + l15) * 40 + q * 8];
      bf16x8 b1 = *(const bf16x8*)&Ss[(j * 16 + l15) * 40 + q * 8];
      am[j]  = __builtin_amdgcn_mfma_f32_16x16x32_bf16(a, b0, am[j], 0, 0, 0);
      as_[j] = __builtin_amdgcn_mfma_f32_16x16x32_bf16(a, b1, as_[j], 0, 0, 0);
    }
  }
  float kld = 0.0f;
  us ztv[4][4];
  #pragma unroll
  for (int j = 0; j < 4; ++j) {
    const int c = j * 16 + l15;
    const float bmv = bm[c], bsv = bs[c];
    #pragma unroll
    for (int r = 0; r < 4; ++r) {
      const int m = m0 + w * 16 + q * 4 + r;
      const float mu = am[j][r] + bmv;
      const float sd = splusf(as_[j][r] + bsv);
      ztv[j][r] = f2b(eps[(size_t)m * Zn + c] * sd + mu);
      const float pm = pm_in[(size_t)m * Zn + c];
      const float ps = ps_in[(size_t)m * Zn + c];
      const float dd = (mu - pm) / ps;
      const float rr = sd / ps;
      kld += dd * dd + rr * rr - 2.0f * __logf(rr) - 1.0f;
    }
  }
  // block_sum's internal __syncthreads also guarantees all waves finished the
  // k-loop LDS reads before we repurpose As/Ms as the zt tile below.
  const float s = block_sum(kld, red);
  if (tid == 0) atomicAdd(kacc, 0.5f * s);
  us* zts = (us*)smemc;              // 64*72*2 = 9216 B (overlaps As+Ms)
  us* Bs = (us*)(smemc + 10240);     // overlaps Ss
  #pragma unroll
  for (int j = 0; j < 4; ++j)
    #pragma unroll
    for (int r = 0; r < 4; ++r)
      zts[(w * 16 + q * 4 + r) * 72 + (j * 16 + l15)] = ztv[j][r];
  for (int nt = 0; nt < 8; ++nt) {
    f32x4 pa[4];
    #pragma unroll
    for (int j = 0; j < 4; ++j) pa[j] = (f32x4){0.f, 0.f, 0.f, 0.f};
    const us* wp = pzW + (size_t)(nt * 64 + srow) * 64 + scb;
    uint4 wv = *(const uint4*)wp;
    for (int k0 = 0; k0 < 64; k0 += 32) {
      __syncthreads();
      *(uint4*)&Bs[srow * 40 + scb] = wv;
      __syncthreads();
      if (k0 == 0) wv = *(const uint4*)(wp + 32);
      bf16x8 a = *(const bf16x8*)&zts[(w * 16 + l15) * 72 + k0 + q * 8];
      #pragma unroll
      for (int j = 0; j < 4; ++j) {
        bf16x8 b = *(const bf16x8*)&Bs[(j * 16 + l15) * 40 + q * 8];
        pa[j] = __builtin_amdgcn_mfma_f32_16x16x32_bf16(a, b, pa[j], 0, 0, 0);
      }
    }
    #pragma unroll
    for (int j = 0; j < 4; ++j) {
      const int col = nt * 64 + j * 16 + l15;
      const float bv = pzb[col];
      #pragma unroll
      for (int r = 0; r < 4; ++r) {
        const int row = m0 + w * 16 + q * 4 + r;
        phiz[(size_t)row * Hn + col] = f2b(fmaxf(pa[j][r] + bv, 0.f));
      }
    }
  }
}

// ================= global kernels =================
__global__ __launch_bounds__(256) void k_gemmA(
    const us* A, const us* W, int ldw, int K, const float* bias, us* C, int ldc)
{
  __shared__ alignas(16) char sm[10240];
  tile_gemmx<1, true, false, false, true>(blockIdx.x, blockIdx.y, A, W, ldw, K,
      nullptr, nullptr, 0, 0, nullptr, 0, bias, C, ldc, sm);
}

__global__ __launch_bounds__(256) void k_gruB(
    const us* A0, const us* Wih, const us* hprev, const us* Whh,
    const float* bih, const float* bhh, us* hnew)
{
  __shared__ alignas(16) char sm[20480];
  tile_gru_fe(blockIdx.x, blockIdx.y, A0, Wih, hprev, Whh, bih, bhh, hnew, sm);
}

__global__ __launch_bounds__(256) void k_statf(
    const us* fh, const us* femW, const float* femb, const us* fesW, const float* fesb,
    const float* eps_f, us* fbuf, float* kacc)
{
  __shared__ alignas(16) char sm[15376];
  stat_dual<1>(blockIdx.x, fh, femW, femb, fesW, fesb, eps_f,
               fbuf, nullptr, nullptr, kacc, sm);
}

// P2: Cpre_gru = phi_f @ rWih[:,1024:1536]^T (g3, 64) | Cpre_dec (64)
__global__ __launch_bounds__(256) void kP2(
    const us* phi_f, const us* rWih, const us* dW1, const float* db1,
    float* Cpre_gru, float* Cpre_dec)
{
  __shared__ alignas(16) char sm[20480];
  const int b = blockIdx.x;
  if (b < 64)
    tile_g3<false>(b & 7, b >> 3, phi_f, rWih + 1024, 1536, nullptr, Cpre_gru, sm);
  else
    tile_gemmx<1, false, true, false, true>((b - 64) & 7, (b - 64) >> 3,
        phi_f, dW1 + 512, 1536, Hn,
        nullptr, nullptr, 0, 0, nullptr, 0, db1, Cpre_dec, 512, sm);
}

// P3: zp0 (64, from h0=0) | zepre0 (64)
__global__ __launch_bounds__(256) void kP3(
    const us* h0, const us* zpW, const float* zpb, us* zp,
    const us* px0, const us* zeW1, const float* zeb1, us* zepre)
{
  __shared__ alignas(16) char sm[10240];
  const int b = blockIdx.x;
  if (b < 64)
    tile_gemmx<1, true, false, false, true>(b & 7, b >> 3, h0, zpW, Hn, Hn,
        nullptr, nullptr, 0, 0, nullptr, 0, zpb, zp, Hn, sm);
  else
    tile_gemmx<2, true, false, false, true>((b - 64) & 7, (b - 64) >> 3,
        px0, zeW1, 1024, Hn, h0, zeW1 + 512, 1024, Hn,
        nullptr, 0, zeb1, zepre, Hn, sm);
}

// P4: ze0 (64) | zpstat0 (8)
__global__ __launch_bounds__(256) void kP4(
    const us* zepre, const us* zeW2, const float* zeb2, us* ze,
    const us* zp, const us* zpmW, const float* zpmb, const us* zpsW, const float* zpsb,
    float* zpm, float* zps)
{
  __shared__ alignas(16) char sm[15376];
  const int b = blockIdx.x;
  if (b < 64)
    tile_gemmx<1, true, false, false, true>(b & 7, b >> 3, zepre, zeW2, Hn, Hn,
        nullptr, nullptr, 0, 0, nullptr, 0, zeb2, ze, Hn, sm);
  else
    stat_dual<0>(b - 64, zp, zpmW, zpmb, zpsW, zpsb,
                 nullptr, nullptr, zpm, zps, nullptr, sm);
}

// D1: zestat+phiz fused (8) | gipre via g3 (64)
__global__ __launch_bounds__(256) void kD1(
    const us* ze, const us* zemW, const float* zemb, const us* zesW, const float* zesb,
    const float* eps_zt, const float* zpm, const float* zps,
    const us* pzW, const float* pzb, us* phiz, float* kacc,
    const us* px_t, const us* rWih, const float* Cpre_gru, float* gipre)
{
  __shared__ alignas(16) char sm[20480];
  const int b = blockIdx.x;
  if (b < 8)
    tile_zestat_phiz(b, ze, zemW, zemb, zesW, zesb, eps_zt, zpm, zps,
                     pzW, pzb, phiz, kacc, sm);
  else
    tile_g3<true>((b - 8) & 7, (b - 8) >> 3, px_t, rWih, 1536, Cpre_gru, gipre, sm);
}

// D2: gru_fin (64) | dtmp (64)
__global__ __launch_bounds__(256) void kD2(
    const us* phiz, const us* rWih, const float* gipre, const float* ghpre,
    const us* hprev, const float* rbih, const float* rbhh, us* hnew,
    const us* dW1, const float* dtmph, us* dtmp)
{
  __shared__ alignas(16) char sm[20480];
  const int b = blockIdx.x;
  if (b < 64)
    tile_gru_fin(b & 7, b >> 3, phiz, rWih, gipre, ghpre, hprev, rbih, rbhh, hnew, sm);
  else
    tile_gemmx<1, true, false, true, false>((b - 64) & 7, (b - 64) >> 3, phiz, dW1, 1536, Hn,
        nullptr, nullptr, 0, 0, dtmph, 512, nullptr, dtmp, Hn, sm);
}

// D3: dec -> phi_x[t] slot (64) | zp' (64) | zepre' (64) | dtmph' (64)
__global__ __launch_bounds__(256) void kD3(
    const us* dtmp, const us* dW2, const float* db2, us* dec_slot,
    const us* hnext, const us* zpW, const float* zpb, us* zp,
    const us* px1, const us* zeW1, const float* zeb1, us* zepre,
    const us* dW1, const float* Cpre_dec, float* dtmph)
{
  __shared__ alignas(16) char sm[10240];
  const int b = blockIdx.x;
  if (b < 64)
    tile_gemmx<1, true, false, false, true>(b & 7, b >> 3, dtmp, dW2, Hn, Hn,
        nullptr, nullptr, 0, 0, nullptr, 0, db2, dec_slot, Hn, sm);
  else if (b < 128)
    tile_gemmx<1, true, false, false, true>((b - 64) & 7, (b - 64) >> 3, hnext, zpW, Hn, Hn,
        nullptr, nullptr, 0, 0, nullptr, 0, zpb, zp, Hn, sm);
  else if (b < 192)
    tile_gemmx<2, true, false, false, true>((b - 128) & 7, (b - 128) >> 3,
        px1, zeW1, 1024, Hn, hnext, zeW1 + 512, 1024, Hn,
        nullptr, 0, zeb1, zepre, Hn, sm);
  else
    tile_gemmx<1, false, true, true, false>((b - 192) & 7, (b - 192) >> 3,
        hnext, dW1 + 1024, 1536, Hn,
        nullptr, nullptr, 0, 0, Cpre_dec, 512, nullptr, dtmph, 512, sm);
}

// D4: ze' (64) | zpstat' (8) | ghpre' via g3 (64)
__global__ __launch_bounds__(256) void kD4(
    const us* zepre, const us* zeW2, const float* zeb2, us* ze,
    const us* zp, const us* zpmW, const float* zpmb, const us* zpsW, const float* zpsb,
    float* zpm, float* zps,
    const us* hnext, const us* rWhh, float* ghpre)
{
  __shared__ alignas(16) char sm[20480];
  const int b = blockIdx.x;
  if (b < 64)
    tile_gemmx<1, true, false, false, true>(b & 7, b >> 3, zepre, zeW2, Hn, Hn,
        nullptr, nullptr, 0, 0, nullptr, 0, zeb2, ze, Hn, sm);
  else if (b < 72)
    stat_dual<0>(b - 64, zp, zpmW, zpmb, zpsW, zpsb,
                 nullptr, nullptr, zpm, zps, nullptr, sm);
  else
    tile_g3<false>((b - 72) & 7, (b - 72) >> 3, hnext, rWhh, Hn, nullptr, ghpre, sm);
}

// nll over ALL timesteps (dec stored in phi_x slots). 64*104 blocks.
__global__ __launch_bounds__(256) void k_nll_all(
    const us* dec_all, const us* dmW, const float* dmb, const float* x, float* nll)
{
  __shared__ alignas(16) char smemc[10256];
  const int b = blockIdx.x;
  const int t = b / 104;
  const int i = b - t * 104;
  const int bx = i % 13, by = i / 13;
  const us* dec = dec_all + (size_t)t * Bn * Hn;
  const float* xt = x + (size_t)t * Bn * Xn;

  us* As = (us*)smemc; us* Bs = (us*)(smemc + 5120);
  float* red = (float*)(smemc + 10240);
  const int tid = threadIdx.x, srow = tid >> 2, scb = (tid & 3) * 8;
  const int lane = tid & 63, w = tid >> 6, l15 = lane & 15, q = lane >> 4;
  const int m0 = by * 64, n0 = bx * 64;
  f32x4 acc[4];
  #pragma unroll
  for (int j = 0; j < 4; ++j) acc[j] = (f32x4){0.f, 0.f, 0.f, 0.f};
  const int wrow = (n0 + srow < Xn) ? (n0 + srow) : (Xn - 1);
  const us* ap = dec + (size_t)(m0 + srow) * Hn + scb;
  const us* wp = dmW + (size_t)wrow * Hn + scb;
  uint4 av = *(const uint4*)ap;
  uint4 wv = *(const uint4*)wp;
  for (int k0 = 0; k0 < Hn; k0 += 32) {
    __syncthreads();
    *(uint4*)&As[srow * 40 + scb] = av;
    *(uint4*)&Bs[srow * 40 + scb] = wv;
    __syncthreads();
    if (k0 + 32 < Hn) {
      av = *(const uint4*)(ap + k0 + 32);
      wv = *(const uint4*)(wp + k0 + 32);
    }
    bf16x8 a = *(const bf16x8*)&As[(w * 16 + l15) * 40 + q * 8];
    #pragma unroll
    for (int j = 0; j < 4; ++j) {
      bf16x8 bb = *(const bf16x8*)&Bs[(j * 16 + l15) * 40 + q * 8];
      acc[j] = __builtin_amdgcn_mfma_f32_16x16x32_bf16(a, bb, acc[j], 0, 0, 0);
    }
  }
  float sum = 0.0f;
  #pragma unroll
  for (int j = 0; j < 4; ++j) {
    const int n = n0 + j * 16 + l15;
    if (n < Xn) {
      const float bv = dmb[n];
      #pragma unroll
      for (int r = 0; r < 4; ++r) {
        const int m = m0 + w * 16 + q * 4 + r;
        const float a = acc[j][r] + bv;
        const float xv = xt[(size_t)m * Xn + n];
        sum += splusf(-a) + (1.0f - xv) * a;
      }
    }
  }
  const float s = block_sum(sum, red);
  if (tid == 0) atomicAdd(nll, s);
}

} // anonymous namespace

extern "C" void kernel_launch(void* const* d_in, const int* in_sizes, int n_in,
                              void* d_out, int out_size, void* d_ws, size_t ws_size,
                              hipStream_t stream)
{
  (void)in_sizes; (void)n_in; (void)out_size;
  const float* x     = (const float*)d_in[0];
  const float* eps_f = (const float*)d_in[1];
  const float* eps_z = (const float*)d_in[2];
  const float* pxW1  = (const float*)d_in[3];
  const float* pxb1  = (const float*)d_in[4];
  const float* pxW2  = (const float*)d_in[5];
  const float* pxb2  = (const float*)d_in[6];
  const float* pzW   = (const float*)d_in[7];
  const float* pzb   = (const float*)d_in[8];
  const float* pfW   = (const float*)d_in[9];
  const float* pfb   = (const float*)d_in[10];
  const float* rWih  = (const float*)d_in[11];
  const float* rWhh  = (const float*)d_in[12];
  const float* rbih  = (const float*)d_in[13];
  const float* rbhh  = (const float*)d_in[14];
  const float* zpW   = (const float*)d_in[15];
  const float* zpb   = (const float*)d_in[16];
  const float* zpmW  = (const float*)d_in[17];
  const float* zpmb  = (const float*)d_in[18];
  const float* zpsW  = (const float*)d_in[19];
  const float* zpsb  = (const float*)d_in[20];
  const float* feWih = (const float*)d_in[21];
  const float* feWhh = (const float*)d_in[22];
  const float* febih = (const float*)d_in[23];
  const float* febhh = (const float*)d_in[24];
  const float* femW  = (const float*)d_in[25];
  const float* femb  = (const float*)d_in[26];
  const float* fesW  = (const float*)d_in[27];
  const float* fesb  = (const float*)d_in[28];
  const float* zeW1  = (const float*)d_in[29];
  const float* zeb1  = (const float*)d_in[30];
  const float* zeW2  = (const float*)d_in[31];
  const float* zeb2  = (const float*)d_in[32];
  const float* zemW  = (const float*)d_in[33];
  const float* zemb  = (const float*)d_in[34];
  const float* zesW  = (const float*)d_in[35];
  const float* zesb  = (const float*)d_in[36];
  const float* dW1   = (const float*)d_in[37];
  const float* db1   = (const float*)d_in[38];
  const float* dW2   = (const float*)d_in[39];
  const float* db2   = (const float*)d_in[40];
  const float* dmW   = (const float*)d_in[41];
  const float* dmb   = (const float*)d_in[42];
  float* out = (float*)d_out;

  char* base = (char*)d_ws;
  size_t off = 0;
  auto ab = [&](size_t bytes) -> void* {
    void* p = base + off;
    off += (bytes + 255) & ~(size_t)255;
    return p;
  };

  // bf16 weights
  us* b_pxW1  = (us*)ab((size_t)512 * XnP * 2);
  us* b_pxW2  = (us*)ab((size_t)512 * 512 * 2);
  us* b_pzW   = (us*)ab((size_t)512 * 64 * 2);
  us* b_pfW   = (us*)ab((size_t)512 * 64 * 2);
  us* b_rWih  = (us*)ab((size_t)1536 * 1536 * 2);
  us* b_rWhh  = (us*)ab((size_t)1536 * 512 * 2);
  us* b_zpW   = (us*)ab((size_t)512 * 512 * 2);
  us* b_zpmW  = (us*)ab((size_t)64 * 512 * 2);
  us* b_zpsW  = (us*)ab((size_t)64 * 512 * 2);
  us* b_feWih = (us*)ab((size_t)1536 * 512 * 2);
  us* b_feWhh = (us*)ab((size_t)1536 * 512 * 2);
  us* b_femW  = (us*)ab((size_t)64 * 512 * 2);
  us* b_fesW  = (us*)ab((size_t)64 * 512 * 2);
  us* b_zeW1  = (us*)ab((size_t)512 * 1024 * 2);
  us* b_zeW2  = (us*)ab((size_t)512 * 512 * 2);
  us* b_zemW  = (us*)ab((size_t)64 * 512 * 2);
  us* b_zesW  = (us*)ab((size_t)64 * 512 * 2);
  us* b_dW1   = (us*)ab((size_t)512 * 1536 * 2);
  us* b_dW2   = (us*)ab((size_t)512 * 512 * 2);
  us* b_dmW   = (us*)ab((size_t)Xn * 512 * 2);

  // activations
  us* phi_x = (us*)ab((size_t)Tn * Bn * Hn * 2);  // doubles as dec_all in Phase D
  us* fh_a  = (us*)ab((size_t)Bn * Hn * 2);
  us* h_a   = (us*)ab((size_t)Bn * Hn * 2);   // adjacent to fh_a (one memset)
  us* fh_b  = (us*)ab((size_t)Bn * Hn * 2);
  us* h_b   = (us*)ab((size_t)Bn * Hn * 2);
  us* fbuf  = (us*)ab((size_t)Bn * Fn * 2);
  us* phi_f = (us*)ab((size_t)Bn * Hn * 2);
  us* zp    = (us*)ab((size_t)Bn * Hn * 2);
  us* zepre = (us*)ab((size_t)Bn * Hn * 2);
  us* ze    = (us*)ab((size_t)Bn * Hn * 2);
  us* phiz  = (us*)ab((size_t)Bn * Hn * 2);
  us* dtmp  = (us*)ab((size_t)Bn * Hn * 2);
  float* zpm = (float*)ab((size_t)Bn * Zn * 4);
  float* zps = (float*)ab((size_t)Bn * Zn * 4);
  float* Cpre_gru = (float*)ab((size_t)Bn * 1536 * 4);
  float* Cpre_dec = (float*)ab((size_t)Bn * 512 * 4);
  float* gipre    = (float*)ab((size_t)Bn * 1536 * 4);
  float* ghpre    = (float*)ab((size_t)Bn * 1536 * 4);
  float* dtmph    = (float*)ab((size_t)Bn * 512 * 4);

  int CH = 16;
  while (CH > 1 && off + (size_t)CH * (Bn * XnP + Bn * Hn) * 2 + 4096 > ws_size) CH >>= 1;
  us* xch  = (us*)ab((size_t)CH * Bn * XnP * 2);
  us* tmpb = (us*)ab((size_t)CH * Bn * Hn * 2);

  hipMemsetAsync(d_out, 0, 3 * sizeof(float), stream);
  hipMemsetAsync(fh_a, 0, 2 * (size_t)Bn * Hn * 2, stream);        // fh_a + h_a
  hipMemsetAsync(ghpre, 0, (size_t)Bn * 1536 * 4, stream);          // gh(h0=0) = 0

  const dim3 blk(256);

  // ---- one fused weight-convert kernel ----
  {
    CvtP cp;
    const float* srcs[19] = {pxW2, pzW, pfW, rWih, rWhh, zpW, zpmW, zpsW,
        feWih, feWhh, femW, fesW, zeW1, zeW2, zemW, zesW, dW1, dW2, dmW};
    us* dsts[19] = {b_pxW2, b_pzW, b_pfW, b_rWih, b_rWhh, b_zpW, b_zpmW, b_zpsW,
        b_feWih, b_feWhh, b_femW, b_fesW, b_zeW1, b_zeW2, b_zemW, b_zesW,
        b_dW1, b_dW2, b_dmW};
    const int ns[19] = {512*512, 512*64, 512*64, 1536*1536, 1536*512,
        512*512, 64*512, 64*512, 1536*512, 1536*512, 64*512, 64*512,
        512*1024, 512*512, 64*512, 64*512, 512*1536, 512*512, 784*512};
    for (int k = 0; k < 19; ++k) { cp.s[k] = srcs[k]; cp.d[k] = dsts[k]; cp.n[k] = ns[k]; }
    cp.pxW1src = pxW1; cp.pxW1dst = b_pxW1;
    k_cvt_all<<<dim3(1024), blk, 0, stream>>>(cp);
  }

  // ---- Phase A: phi_x ----
  for (int c = 0; c < Tn / CH; ++c) {
    const size_t nx = (size_t)CH * Bn * XnP;
    cvt_pad<<<dim3((unsigned)((nx + 255) / 256)), blk, 0, stream>>>(
        x + (size_t)c * CH * Bn * Xn, xch, Xn, XnP, (int)nx);
    const dim3 gA(8, CH * Bn / 64);
    k_gemmA<<<gA, blk, 0, stream>>>(xch, b_pxW1, XnP, XnP, pxb1, tmpb, Hn);
    k_gemmA<<<gA, blk, 0, stream>>>(tmpb, b_pxW2, Hn, Hn, pxb2,
                                    phi_x + (size_t)c * CH * Bn * Hn, Hn);
  }

  // ---- Phase B: f-encoder GRU ----
  us* fc = fh_a; us* fn2 = fh_b;
  for (int t = 0; t < Tn; ++t) {
    k_gruB<<<dim3(8, 8), blk, 0, stream>>>(
        phi_x + (size_t)t * Bn * Hn, b_feWih, fc, b_feWhh, febih, febhh, fn2);
    us* sw = fc; fc = fn2; fn2 = sw;
  }

  // ---- Phase C: f stats (final hidden back in fh_a since Tn even) ----
  k_statf<<<dim3(8), blk, 0, stream>>>(fh_a, b_femW, femb, b_fesW, fesb, eps_f, fbuf, out + 0);

  // ---- Prologue ----
  k_gemmA<<<dim3(8, 8), blk, 0, stream>>>(fbuf, b_pfW, Fn, Fn, pfb, phi_f, Hn);
  kP2<<<dim3(128), blk, 0, stream>>>(phi_f, b_rWih, b_dW1, db1, Cpre_gru, Cpre_dec);
  kP3<<<dim3(128), blk, 0, stream>>>(h_a, b_zpW, zpb, zp, phi_x, b_zeW1, zeb1, zepre);
  kP4<<<dim3(72), blk, 0, stream>>>(zepre, b_zeW2, zeb2, ze,
                                    zp, b_zpmW, zpmb, b_zpsW, zpsb, zpm, zps);

  // ---- Phase D: 4 launches per timestep; dec lands in phi_x[t] slot ----
  for (int t = 0; t < Tn; ++t) {
    const us* hcur = (t & 1) ? h_b : h_a;
    us* hnext      = (t & 1) ? h_a : h_b;
    const bool last = (t == Tn - 1);
    const us* px_t = phi_x + (size_t)t * Bn * Hn;

    kD1<<<dim3(72), blk, 0, stream>>>(
        ze, b_zemW, zemb, b_zesW, zesb, eps_z + (size_t)t * Bn * Zn, zpm, zps,
        b_pzW, pzb, phiz, out + 1, px_t, b_rWih, Cpre_gru, gipre);

    kD2<<<dim3(128), blk, 0, stream>>>(
        phiz, b_rWih, gipre, ghpre, hcur, rbih, rbhh, hnext,
        b_dW1, (t == 0 ? Cpre_dec : dtmph), dtmp);

    kD3<<<dim3(last ? 64 : 256), blk, 0, stream>>>(
        dtmp, b_dW2, db2, phi_x + (size_t)t * Bn * Hn,
        hnext, b_zpW, zpb, zp,
        phi_x + (size_t)(t + 1) * Bn * Hn, b_zeW1, zeb1, zepre,
        b_dW1, Cpre_dec, dtmph);

    if (!last)
      kD4<<<dim3(136), blk, 0, stream>>>(
          zepre, b_zeW2, zeb2, ze,
          zp, b_zpmW, zpmb, b_zpsW, zpsb, zpm, zps,
          hnext, b_rWhh, ghpre);
  }

  // ---- nll over all timesteps (fully parallel) ----
  k_nll_all<<<dim3(Tn * 104), blk, 0, stream>>>(phi_x, b_dmW, dmb, x, out + 2);
}

// Round 9
// 6952.419 us; speedup vs baseline: 4.5921x; 1.0016x over previous
//
#include <hip/hip_runtime.h>
#include <cmath>

namespace {

constexpr int Tn = 64;
constexpr int Bn = 512;
constexpr int Xn = 784;
constexpr int XnP = 800;
constexpr int Fn = 64;
constexpr int Zn = 64;
constexpr int Hn = 512;

typedef unsigned short us;
typedef __attribute__((ext_vector_type(8))) short bf16x8;
typedef __attribute__((ext_vector_type(4))) float f32x4;

__device__ __forceinline__ us f2b(float v) {
  unsigned int u = __float_as_uint(v);
  return (us)((u + 0x7FFFu + ((u >> 16) & 1u)) >> 16);
}
__device__ __forceinline__ float b2f(us u) { return __uint_as_float(((unsigned int)u) << 16); }
__device__ __forceinline__ float sigmf(float v) { return 1.0f / (1.0f + __expf(-v)); }
__device__ __forceinline__ float splusf(float v) {
  return v > 0.0f ? (v + log1pf(__expf(-v))) : log1pf(__expf(v));
}
__device__ __forceinline__ float block_sum(float v, float* red) {
  #pragma unroll
  for (int off = 32; off > 0; off >>= 1) v += __shfl_down(v, off, 64);
  if ((threadIdx.x & 63) == 0) red[threadIdx.x >> 6] = v;
  __syncthreads();
  float s = 0.0f;
  if (threadIdx.x == 0) s = red[0] + red[1] + red[2] + red[3];
  return s;
}

// ---- fused weight converter ----
struct CvtP {
  const float* s[19];
  us* d[19];
  int n[19];
  const float* pxW1src;
  us* pxW1dst;
};
__global__ __launch_bounds__(256) void k_cvt_all(CvtP p) {
  const int gtid = blockIdx.x * 256 + threadIdx.x;
  const int gnt = gridDim.x * 256;
  for (int k = 0; k < 19; ++k) {
    const float* s = p.s[k]; us* d = p.d[k]; const int n = p.n[k];
    for (int i = gtid; i < n; i += gnt) d[i] = f2b(s[i]);
  }
  for (int i = gtid; i < 512 * XnP; i += gnt) {
    const int r = i / XnP, c = i - r * XnP;
    p.pxW1dst[i] = (c < Xn) ? f2b(p.pxW1src[(size_t)r * Xn + c]) : (us)0;
  }
}

__global__ __launch_bounds__(256) void cvt_pad(
    const float* __restrict__ s, us* __restrict__ d, int C, int Cp, int n) {
  int i = blockIdx.x * 256 + threadIdx.x;
  if (i < n) {
    int r = i / Cp, c = i - r * Cp;
    d[i] = (c < C) ? f2b(s[(size_t)r * C + c]) : (us)0;
  }
}

// ================= tile device functions =================
// 64x64 GEMM tile with optional fp32 accumulator init, fp32/bf16 out, bias, relu.
// smem >= 10240 B.
template <int NSEG, bool RELU, bool F32OUT, bool HASINIT, bool HASBIAS>
__device__ void tile_gemmx(
    int bx, int by,
    const us* A0, const us* W0, int ldw0, int K0,
    const us* A1, const us* W1, int ldw1, int K1,
    const float* initC, int ldi, const float* bias,
    void* Cout, int ldc, char* smemc)
{
  us* As = (us*)smemc; us* Bs = (us*)(smemc + 5120);
  const int tid = threadIdx.x, srow = tid >> 2, scb = (tid & 3) * 8;
  const int lane = tid & 63, w = tid >> 6, l15 = lane & 15, q = lane >> 4;
  const int m0 = by * 64, n0 = bx * 64;
  f32x4 acc[4];
  if (HASINIT) {
    #pragma unroll
    for (int j = 0; j < 4; ++j)
      #pragma unroll
      for (int r = 0; r < 4; ++r)
        acc[j][r] = initC[(size_t)(m0 + w * 16 + q * 4 + r) * ldi + n0 + j * 16 + l15];
  } else {
    #pragma unroll
    for (int j = 0; j < 4; ++j) acc[j] = (f32x4){0.f, 0.f, 0.f, 0.f};
  }
  #pragma unroll
  for (int seg = 0; seg < NSEG; ++seg) {
    const us* A = (seg == 0) ? A0 : A1;
    const us* W = (seg == 0) ? W0 : W1;
    const int ldw = (seg == 0) ? ldw0 : ldw1;
    const int K   = (seg == 0) ? K0 : K1;
    const us* ap = A + (size_t)(m0 + srow) * K + scb;
    const us* wp = W + (size_t)(n0 + srow) * ldw + scb;
    uint4 av = *(const uint4*)ap;
    uint4 wv = *(const uint4*)wp;
    for (int k0 = 0; k0 < K; k0 += 32) {
      __syncthreads();
      *(uint4*)&As[srow * 40 + scb] = av;
      *(uint4*)&Bs[srow * 40 + scb] = wv;
      __syncthreads();
      if (k0 + 32 < K) {
        av = *(const uint4*)(ap + k0 + 32);
        wv = *(const uint4*)(wp + k0 + 32);
      }
      bf16x8 a = *(const bf16x8*)&As[(w * 16 + l15) * 40 + q * 8];
      #pragma unroll
      for (int j = 0; j < 4; ++j) {
        bf16x8 b = *(const bf16x8*)&Bs[(j * 16 + l15) * 40 + q * 8];
        acc[j] = __builtin_amdgcn_mfma_f32_16x16x32_bf16(a, b, acc[j], 0, 0, 0);
      }
    }
  }
  #pragma unroll
  for (int j = 0; j < 4; ++j) {
    const int col = n0 + j * 16 + l15;
    const float bv = HASBIAS ? bias[col] : 0.f;
    #pragma unroll
    for (int r = 0; r < 4; ++r) {
      const int row = m0 + w * 16 + q * 4 + r;
      float v = acc[j][r] + bv;
      if (RELU) v = fmaxf(v, 0.f);
      if (F32OUT) ((float*)Cout)[(size_t)row * ldc + col] = v;
      else        ((us*)Cout)[(size_t)row * ldc + col] = f2b(v);
    }
  }
}

// Phase-B GRU tile (2 segs: gi = A0@Wih^T, gh = h@Whh^T). smem >= 20480 B.
__device__ void tile_gru_fe(
    int bx, int by,
    const us* A0, const us* Wih,
    const us* hprev, const us* Whh,
    const float* bih, const float* bhh,
    us* hnew, char* smemc)
{
  us* Asm = (us*)smemc; us* Rs = (us*)(smemc + 5120);
  us* Zs = (us*)(smemc + 10240); us* Ns = (us*)(smemc + 15360);
  const int tid = threadIdx.x, srow = tid >> 2, scb = (tid & 3) * 8;
  const int lane = tid & 63, w = tid >> 6, l15 = lane & 15, q = lane >> 4;
  const int m0 = by * 64, c0 = bx * 64;
  f32x4 aR[4], aZ[4], aI[4], aH[4];
  #pragma unroll
  for (int j = 0; j < 4; ++j) {
    aR[j] = (f32x4){0.f, 0.f, 0.f, 0.f}; aZ[j] = aR[j]; aI[j] = aR[j]; aH[j] = aR[j];
  }
  #pragma unroll
  for (int seg = 0; seg < 2; ++seg) {
    const bool hseg = (seg == 1);
    const us* A  = hseg ? hprev : A0;
    const us* Wb = hseg ? Whh : Wih;
    const us* ap = A + (size_t)(m0 + srow) * Hn + scb;
    const us* wr = Wb + (size_t)(c0 + srow) * Hn + scb;
    const us* wz = wr + (size_t)Hn * Hn;
    const us* wn = wz + (size_t)Hn * Hn;
    uint4 av = *(const uint4*)ap;
    uint4 rv = *(const uint4*)wr;
    uint4 zv = *(const uint4*)wz;
    uint4 nv = *(const uint4*)wn;
    for (int k0 = 0; k0 < Hn; k0 += 32) {
      __syncthreads();
      *(uint4*)&Asm[srow * 40 + scb] = av;
      *(uint4*)&Rs[srow * 40 + scb] = rv;
      *(uint4*)&Zs[srow * 40 + scb] = zv;
      *(uint4*)&Ns[srow * 40 + scb] = nv;
      __syncthreads();
      if (k0 + 32 < Hn) {
        av = *(const uint4*)(ap + k0 + 32);
        rv = *(const uint4*)(wr + k0 + 32);
        zv = *(const uint4*)(wz + k0 + 32);
        nv = *(const uint4*)(wn + k0 + 32);
      }
      bf16x8 a = *(const bf16x8*)&Asm[(w * 16 + l15) * 40 + q * 8];
      #pragma unroll
      for (int j = 0; j < 4; ++j) {
        bf16x8 br = *(const bf16x8*)&Rs[(j * 16 + l15) * 40 + q * 8];
        bf16x8 bz = *(const bf16x8*)&Zs[(j * 16 + l15) * 40 + q * 8];
        bf16x8 bn = *(const bf16x8*)&Ns[(j * 16 + l15) * 40 + q * 8];
        aR[j] = __builtin_amdgcn_mfma_f32_16x16x32_bf16(a, br, aR[j], 0, 0, 0);
        aZ[j] = __builtin_amdgcn_mfma_f32_16x16x32_bf16(a, bz, aZ[j], 0, 0, 0);
        if (hseg) aH[j] = __builtin_amdgcn_mfma_f32_16x16x32_bf16(a, bn, aH[j], 0, 0, 0);
        else      aI[j] = __builtin_amdgcn_mfma_f32_16x16x32_bf16(a, bn, aI[j], 0, 0, 0);
      }
    }
  }
  #pragma unroll
  for (int j = 0; j < 4; ++j) {
    const int c = c0 + j * 16 + l15;
    const float bR = bih[c] + bhh[c];
    const float bZ = bih[Hn + c] + bhh[Hn + c];
    const float bI = bih[2 * Hn + c];
    const float bH = bhh[2 * Hn + c];
    #pragma unroll
    for (int r = 0; r < 4; ++r) {
      const int m = m0 + w * 16 + q * 4 + r;
      const float h = b2f(hprev[(size_t)m * Hn + c]);
      const float rg = sigmf(aR[j][r] + bR);
      const float zg = sigmf(aZ[j][r] + bZ);
      const float ng = tanhf(aI[j][r] + bI + rg * (aH[j][r] + bH));
      hnew[(size_t)m * Hn + c] = f2b((1.0f - zg) * ng + zg * h);
    }
  }
}

// Phase-D GRU final tile.
__device__ void tile_gru_fin(
    int bx, int by,
    const us* phiz, const us* rWih,
    const float* gipre, const float* ghpre,
    const us* hprev,
    const float* bih, const float* bhh,
    us* hnew, char* smemc)
{
  us* Asm = (us*)smemc; us* Rs = (us*)(smemc + 5120);
  us* Zs = (us*)(smemc + 10240); us* Ns = (us*)(smemc + 15360);
  const int tid = threadIdx.x, srow = tid >> 2, scb = (tid & 3) * 8;
  const int lane = tid & 63, w = tid >> 6, l15 = lane & 15, q = lane >> 4;
  const int m0 = by * 64, c0 = bx * 64;
  f32x4 aR[4], aZ[4], aI[4];
  float aH[4][4];
  #pragma unroll
  for (int j = 0; j < 4; ++j) {
    const int c = c0 + j * 16 + l15;
    #pragma unroll
    for (int r = 0; r < 4; ++r) {
      const size_t row = (size_t)(m0 + w * 16 + q * 4 + r) * 1536;
      aR[j][r] = gipre[row + c] + ghpre[row + c];
      aZ[j][r] = gipre[row + 512 + c] + ghpre[row + 512 + c];
      aI[j][r] = gipre[row + 1024 + c];
      aH[j][r] = ghpre[row + 1024 + c];
    }
  }
  const us* ap = phiz + (size_t)(m0 + srow) * Hn + scb;
  const us* wr = rWih + (size_t)(c0 + srow) * 1536 + 512 + scb;
  const us* wz = wr + (size_t)512 * 1536;
  const us* wn = wz + (size_t)512 * 1536;
  uint4 av = *(const uint4*)ap;
  uint4 rv = *(const uint4*)wr;
  uint4 zv = *(const uint4*)wz;
  uint4 nv = *(const uint4*)wn;
  for (int k0 = 0; k0 < Hn; k0 += 32) {
    __syncthreads();
    *(uint4*)&Asm[srow * 40 + scb] = av;
    *(uint4*)&Rs[srow * 40 + scb] = rv;
    *(uint4*)&Zs[srow * 40 + scb] = zv;
    *(uint4*)&Ns[srow * 40 + scb] = nv;
    __syncthreads();
    if (k0 + 32 < Hn) {
      av = *(const uint4*)(ap + k0 + 32);
      rv = *(const uint4*)(wr + k0 + 32);
      zv = *(const uint4*)(wz + k0 + 32);
      nv = *(const uint4*)(wn + k0 + 32);
    }
    bf16x8 a = *(const bf16x8*)&Asm[(w * 16 + l15) * 40 + q * 8];
    #pragma unroll
    for (int j = 0; j < 4; ++j) {
      bf16x8 br = *(const bf16x8*)&Rs[(j * 16 + l15) * 40 + q * 8];
      bf16x8 bz = *(const bf16x8*)&Zs[(j * 16 + l15) * 40 + q * 8];
      bf16x8 bn = *(const bf16x8*)&Ns[(j * 16 + l15) * 40 + q * 8];
      aR[j] = __builtin_amdgcn_mfma_f32_16x16x32_bf16(a, br, aR[j], 0, 0, 0);
      aZ[j] = __builtin_amdgcn_mfma_f32_16x16x32_bf16(a, bz, aZ[j], 0, 0, 0);
      aI[j] = __builtin_amdgcn_mfma_f32_16x16x32_bf16(a, bn, aI[j], 0, 0, 0);
    }
  }
  #pragma unroll
  for (int j = 0; j < 4; ++j) {
    const int c = c0 + j * 16 + l15;
    const float bR = bih[c] + bhh[c];
    const float bZ = bih[Hn + c] + bhh[Hn + c];
    const float bI = bih[2 * Hn + c];
    const float bH = bhh[2 * Hn + c];
    #pragma unroll
    for (int r = 0; r < 4; ++r) {
      const int m = m0 + w * 16 + q * 4 + r;
      const float h = b2f(hprev[(size_t)m * Hn + c]);
      const float rg = sigmf(aR[j][r] + bR);
      const float zg = sigmf(aZ[j][r] + bZ);
      const float ng = tanhf(aI[j][r] + bI + rg * (aH[j][r] + bH));
      hnew[(size_t)m * Hn + c] = f2b((1.0f - zg) * ng + zg * h);
    }
  }
}

// dual-head stats tile, MODE 0 (prior heads -> fp32) / MODE 1 (f stats + kld).
// smem >= 15376 B.
template <int MODE>
__device__ void stat_dual(int vb,
    const us* Ain, const us* Wm, const float* bm, const us* Ws, const float* bs,
    const float* eps,
    us* o0b, float* o_pm, float* o_ps, float* kacc, char* smemc)
{
  us* As = (us*)smemc; us* Ms = (us*)(smemc + 5120); us* Ss = (us*)(smemc + 10240);
  float* red = (float*)(smemc + 15360);
  const int tid = threadIdx.x, srow = tid >> 2, scb = (tid & 3) * 8;
  const int lane = tid & 63, w = tid >> 6, l15 = lane & 15, q = lane >> 4;
  const int m0 = vb * 64;
  f32x4 am[4], as_[4];
  #pragma unroll
  for (int j = 0; j < 4; ++j) { am[j] = (f32x4){0.f, 0.f, 0.f, 0.f}; as_[j] = am[j]; }
  const us* ap = Ain + (size_t)(m0 + srow) * Hn + scb;
  const us* mp = Wm + (size_t)srow * Hn + scb;
  const us* sp = Ws + (size_t)srow * Hn + scb;
  uint4 av = *(const uint4*)ap;
  uint4 mv = *(const uint4*)mp;
  uint4 sv = *(const uint4*)sp;
  for (int k0 = 0; k0 < Hn; k0 += 32) {
    __syncthreads();
    *(uint4*)&As[srow * 40 + scb] = av;
    *(uint4*)&Ms[srow * 40 + scb] = mv;
    *(uint4*)&Ss[srow * 40 + scb] = sv;
    __syncthreads();
    if (k0 + 32 < Hn) {
      av = *(const uint4*)(ap + k0 + 32);
      mv = *(const uint4*)(mp + k0 + 32);
      sv = *(const uint4*)(sp + k0 + 32);
    }
    bf16x8 a = *(const bf16x8*)&As[(w * 16 + l15) * 40 + q * 8];
    #pragma unroll
    for (int j = 0; j < 4; ++j) {
      bf16x8 b0 = *(const bf16x8*)&Ms[(j * 16 + l15) * 40 + q * 8];
      bf16x8 b1 = *(const bf16x8*)&Ss[(j * 16 + l15) * 40 + q * 8];
      am[j]  = __builtin_amdgcn_mfma_f32_16x16x32_bf16(a, b0, am[j], 0, 0, 0);
      as_[j] = __builtin_amdgcn_mfma_f32_16x16x32_bf16(a, b1, as_[j], 0, 0, 0);
    }
  }
  float kld = 0.0f;
  #pragma unroll
  for (int j = 0; j < 4; ++j) {
    const int c = j * 16 + l15;
    const float bmv = bm[c], bsv = bs[c];
    #pragma unroll
    for (int r = 0; r < 4; ++r) {
      const int m = m0 + w * 16 + q * 4 + r;
      const float mu = am[j][r] + bmv;
      const float sd = splusf(as_[j][r] + bsv);
      if (MODE == 0) {
        o_pm[(size_t)m * Zn + c] = mu;
        o_ps[(size_t)m * Zn + c] = sd;
      } else {
        o0b[(size_t)m * Zn + c] = f2b(eps[(size_t)m * Zn + c] * sd + mu);
        kld += mu * mu + sd * sd - 2.0f * __logf(sd) - 1.0f;
      }
    }
  }
  if (MODE != 0) {
    const float s = block_sum(kld, red);
    if (tid == 0) atomicAdd(kacc, 0.5f * s);
  }
}

// zestat (prior-KLD) fused with phiz = relu(zt @ pzW^T + pzb); zt stays in LDS.
// smem >= 20480 B.
__device__ void tile_zestat_phiz(int vb,
    const us* ze, const us* Wm, const float* bm, const us* Ws, const float* bs,
    const float* eps, const float* pm_in, const float* ps_in,
    const us* pzW, const float* pzb, us* phiz,
    float* kacc, char* smemc)
{
  us* As = (us*)smemc; us* Ms = (us*)(smemc + 5120); us* Ss = (us*)(smemc + 10240);
  float* red = (float*)(smemc + 15360);
  const int tid = threadIdx.x, srow = tid >> 2, scb = (tid & 3) * 8;
  const int lane = tid & 63, w = tid >> 6, l15 = lane & 15, q = lane >> 4;
  const int m0 = vb * 64;
  f32x4 am[4], as_[4];
  #pragma unroll
  for (int j = 0; j < 4; ++j) { am[j] = (f32x4){0.f, 0.f, 0.f, 0.f}; as_[j] = am[j]; }
  const us* ap = ze + (size_t)(m0 + srow) * Hn + scb;
  const us* mp = Wm + (size_t)srow * Hn + scb;
  const us* sp = Ws + (size_t)srow * Hn + scb;
  uint4 av = *(const uint4*)ap;
  uint4 mv = *(const uint4*)mp;
  uint4 sv = *(const uint4*)sp;
  for (int k0 = 0; k0 < Hn; k0 += 32) {
    __syncthreads();
    *(uint4*)&As[srow * 40 + scb] = av;
    *(uint4*)&Ms[srow * 40 + scb] = mv;
    *(uint4*)&Ss[srow * 40 + scb] = sv;
    __syncthreads();
    if (k0 + 32 < Hn) {
      av = *(const uint4*)(ap + k0 + 32);
      mv = *(const uint4*)(mp + k0 + 32);
      sv = *(const uint4*)(sp + k0 + 32);
    }
    bf16x8 a = *(const bf16x8*)&As[(w * 16 + l15) * 40 + q * 8];
    #pragma unroll
    for (int j = 0; j < 4; ++j) {
      bf16x8 b0 = *(const bf16x8*)&Ms[(j * 16 + l15) * 40 + q * 8];
      bf16x8 b1 = *(const bf16x8*)&Ss[(j * 16 + l15) * 40 + q * 8];
      am[j]  = __builtin_amdgcn_mfma_f32_16x16x32_bf16(a, b0, am[j], 0, 0, 0);
      as_[j] = __builtin_amdgcn_mfma_f32_16x16x32_bf16(a, b1, as_[j], 0, 0, 0);
    }
  }
  float kld = 0.0f;
  us ztv[4][4];
  #pragma unroll
  for (int j = 0; j < 4; ++j) {
    const int c = j * 16 + l15;
    const float bmv = bm[c], bsv = bs[c];
    #pragma unroll
    for (int r = 0; r < 4; ++r) {
      const int m = m0 + w * 16 + q * 4 + r;
      const float mu = am[j][r] + bmv;
      const float sd = splusf(as_[j][r] + bsv);
      ztv[j][r] = f2b(eps[(size_t)m * Zn + c] * sd + mu);
      const float pm = pm_in[(size_t)m * Zn + c];
      const float ps = ps_in[(size_t)m * Zn + c];
      const float dd = (mu - pm) / ps;
      const float rr = sd / ps;
      kld += dd * dd + rr * rr - 2.0f * __logf(rr) - 1.0f;
    }
  }
  // block_sum's internal __syncthreads also guarantees all waves finished the
  // k-loop LDS reads before we repurpose As/Ms as the zt tile below.
  const float s = block_sum(kld, red);
  if (tid == 0) atomicAdd(kacc, 0.5f * s);
  us* zts = (us*)smemc;              // 64*72*2 = 9216 B (overlaps As+Ms)
  us* Bs = (us*)(smemc + 10240);     // overlaps Ss
  #pragma unroll
  for (int j = 0; j < 4; ++j)
    #pragma unroll
    for (int r = 0; r < 4; ++r)
      zts[(w * 16 + q * 4 + r) * 72 + (j * 16 + l15)] = ztv[j][r];
  for (int nt = 0; nt < 8; ++nt) {
    f32x4 pa[4];
    #pragma unroll
    for (int j = 0; j < 4; ++j) pa[j] = (f32x4){0.f, 0.f, 0.f, 0.f};
    const us* wp = pzW + (size_t)(nt * 64 + srow) * 64 + scb;
    uint4 wv = *(const uint4*)wp;
    for (int k0 = 0; k0 < 64; k0 += 32) {
      __syncthreads();
      *(uint4*)&Bs[srow * 40 + scb] = wv;
      __syncthreads();
      if (k0 == 0) wv = *(const uint4*)(wp + 32);
      bf16x8 a = *(const bf16x8*)&zts[(w * 16 + l15) * 72 + k0 + q * 8];
      #pragma unroll
      for (int j = 0; j < 4; ++j) {
        bf16x8 b = *(const bf16x8*)&Bs[(j * 16 + l15) * 40 + q * 8];
        pa[j] = __builtin_amdgcn_mfma_f32_16x16x32_bf16(a, b, pa[j], 0, 0, 0);
      }
    }
    #pragma unroll
    for (int j = 0; j < 4; ++j) {
      const int col = nt * 64 + j * 16 + l15;
      const float bv = pzb[col];
      #pragma unroll
      for (int r = 0; r < 4; ++r) {
        const int row = m0 + w * 16 + q * 4 + r;
        phiz[(size_t)row * Hn + col] = f2b(fmaxf(pa[j][r] + bv, 0.f));
      }
    }
  }
}

// ================= global kernels =================
__global__ __launch_bounds__(256) void k_gemmA(
    const us* A, const us* W, int ldw, int K, const float* bias, us* C, int ldc)
{
  __shared__ alignas(16) char sm[10240];
  tile_gemmx<1, true, false, false, true>(blockIdx.x, blockIdx.y, A, W, ldw, K,
      nullptr, nullptr, 0, 0, nullptr, 0, bias, C, ldc, sm);
}

__global__ __launch_bounds__(256) void k_gruB(
    const us* A0, const us* Wih, const us* hprev, const us* Whh,
    const float* bih, const float* bhh, us* hnew)
{
  __shared__ alignas(16) char sm[20480];
  tile_gru_fe(blockIdx.x, blockIdx.y, A0, Wih, hprev, Whh, bih, bhh, hnew, sm);
}

__global__ __launch_bounds__(256) void k_statf(
    const us* fh, const us* femW, const float* femb, const us* fesW, const float* fesb,
    const float* eps_f, us* fbuf, float* kacc)
{
  __shared__ alignas(16) char sm[15376];
  stat_dual<1>(blockIdx.x, fh, femW, femb, fesW, fesb, eps_f,
               fbuf, nullptr, nullptr, kacc, sm);
}

// P2: Cpre_gru = phi_f @ rWih[:,1024:1536]^T (192) | Cpre_dec (64)
__global__ __launch_bounds__(256) void kP2(
    const us* phi_f, const us* rWih, const us* dW1, const float* db1,
    float* Cpre_gru, float* Cpre_dec)
{
  __shared__ alignas(16) char sm[10240];
  const int b = blockIdx.x;
  if (b < 192)
    tile_gemmx<1, false, true, false, false>(b % 24, b / 24, phi_f, rWih + 1024, 1536, Hn,
        nullptr, nullptr, 0, 0, nullptr, 0, nullptr, Cpre_gru, 1536, sm);
  else
    tile_gemmx<1, false, true, false, true>((b - 192) & 7, (b - 192) >> 3,
        phi_f, dW1 + 512, 1536, Hn,
        nullptr, nullptr, 0, 0, nullptr, 0, db1, Cpre_dec, 512, sm);
}

// P3: zp0 (64, from h0=0) | zepre0 (64)
__global__ __launch_bounds__(256) void kP3(
    const us* h0, const us* zpW, const float* zpb, us* zp,
    const us* px0, const us* zeW1, const float* zeb1, us* zepre)
{
  __shared__ alignas(16) char sm[10240];
  const int b = blockIdx.x;
  if (b < 64)
    tile_gemmx<1, true, false, false, true>(b & 7, b >> 3, h0, zpW, Hn, Hn,
        nullptr, nullptr, 0, 0, nullptr, 0, zpb, zp, Hn, sm);
  else
    tile_gemmx<2, true, false, false, true>((b - 64) & 7, (b - 64) >> 3,
        px0, zeW1, 1024, Hn, h0, zeW1 + 512, 1024, Hn,
        nullptr, 0, zeb1, zepre, Hn, sm);
}

// P4: ze0 (64) | zpstat0 (8)
__global__ __launch_bounds__(256) void kP4(
    const us* zepre, const us* zeW2, const float* zeb2, us* ze,
    const us* zp, const us* zpmW, const float* zpmb, const us* zpsW, const float* zpsb,
    float* zpm, float* zps)
{
  __shared__ alignas(16) char sm[15376];
  const int b = blockIdx.x;
  if (b < 64)
    tile_gemmx<1, true, false, false, true>(b & 7, b >> 3, zepre, zeW2, Hn, Hn,
        nullptr, nullptr, 0, 0, nullptr, 0, zeb2, ze, Hn, sm);
  else
    stat_dual<0>(b - 64, zp, zpmW, zpmb, zpsW, zpsb,
                 nullptr, nullptr, zpm, zps, nullptr, sm);
}

// D1: zestat+phiz fused (8) | gipre = px_t @ rWih[:,0:512]^T + Cpre_gru (192)
__global__ __launch_bounds__(256) void kD1(
    const us* ze, const us* zemW, const float* zemb, const us* zesW, const float* zesb,
    const float* eps_zt, const float* zpm, const float* zps,
    const us* pzW, const float* pzb, us* phiz, float* kacc,
    const us* px_t, const us* rWih, const float* Cpre_gru, float* gipre)
{
  __shared__ alignas(16) char sm[20480];
  const int b = blockIdx.x;
  if (b < 8)
    tile_zestat_phiz(b, ze, zemW, zemb, zesW, zesb, eps_zt, zpm, zps,
                     pzW, pzb, phiz, kacc, sm);
  else {
    const int tb = b - 8;
    tile_gemmx<1, false, true, true, false>(tb % 24, tb / 24, px_t, rWih, 1536, Hn,
        nullptr, nullptr, 0, 0, Cpre_gru, 1536, nullptr, gipre, 1536, sm);
  }
}

// D2: gru_fin (64) | dtmp (64)
__global__ __launch_bounds__(256) void kD2(
    const us* phiz, const us* rWih, const float* gipre, const float* ghpre,
    const us* hprev, const float* rbih, const float* rbhh, us* hnew,
    const us* dW1, const float* dtmph, us* dtmp)
{
  __shared__ alignas(16) char sm[20480];
  const int b = blockIdx.x;
  if (b < 64)
    tile_gru_fin(b & 7, b >> 3, phiz, rWih, gipre, ghpre, hprev, rbih, rbhh, hnew, sm);
  else
    tile_gemmx<1, true, false, true, false>((b - 64) & 7, (b - 64) >> 3, phiz, dW1, 1536, Hn,
        nullptr, nullptr, 0, 0, dtmph, 512, nullptr, dtmp, Hn, sm);
}

// D3: dec -> phi_x[t] slot (64) | zp' (64) | zepre' (64) | dtmph' (64)
__global__ __launch_bounds__(256) void kD3(
    const us* dtmp, const us* dW2, const float* db2, us* dec_slot,
    const us* hnext, const us* zpW, const float* zpb, us* zp,
    const us* px1, const us* zeW1, const float* zeb1, us* zepre,
    const us* dW1, const float* Cpre_dec, float* dtmph)
{
  __shared__ alignas(16) char sm[10240];
  const int b = blockIdx.x;
  if (b < 64)
    tile_gemmx<1, true, false, false, true>(b & 7, b >> 3, dtmp, dW2, Hn, Hn,
        nullptr, nullptr, 0, 0, nullptr, 0, db2, dec_slot, Hn, sm);
  else if (b < 128)
    tile_gemmx<1, true, false, false, true>((b - 64) & 7, (b - 64) >> 3, hnext, zpW, Hn, Hn,
        nullptr, nullptr, 0, 0, nullptr, 0, zpb, zp, Hn, sm);
  else if (b < 192)
    tile_gemmx<2, true, false, false, true>((b - 128) & 7, (b - 128) >> 3,
        px1, zeW1, 1024, Hn, hnext, zeW1 + 512, 1024, Hn,
        nullptr, 0, zeb1, zepre, Hn, sm);
  else
    tile_gemmx<1, false, true, true, false>((b - 192) & 7, (b - 192) >> 3,
        hnext, dW1 + 1024, 1536, Hn,
        nullptr, nullptr, 0, 0, Cpre_dec, 512, nullptr, dtmph, 512, sm);
}

// D4: ze' (64) | zpstat' (8) | ghpre' = hnext @ rWhh^T (192)
__global__ __launch_bounds__(256) void kD4(
    const us* zepre, const us* zeW2, const float* zeb2, us* ze,
    const us* zp, const us* zpmW, const float* zpmb, const us* zpsW, const float* zpsb,
    float* zpm, float* zps,
    const us* hnext, const us* rWhh, float* ghpre)
{
  __shared__ alignas(16) char sm[15376];
  const int b = blockIdx.x;
  if (b < 64)
    tile_gemmx<1, true, false, false, true>(b & 7, b >> 3, zepre, zeW2, Hn, Hn,
        nullptr, nullptr, 0, 0, nullptr, 0, zeb2, ze, Hn, sm);
  else if (b < 72)
    stat_dual<0>(b - 64, zp, zpmW, zpmb, zpsW, zpsb,
                 nullptr, nullptr, zpm, zps, nullptr, sm);
  else {
    const int tb = b - 72;
    tile_gemmx<1, false, true, false, false>(tb % 24, tb / 24, hnext, rWhh, Hn, Hn,
        nullptr, nullptr, 0, 0, nullptr, 0, nullptr, ghpre, 1536, sm);
  }
}

// nll over ALL timesteps (dec stored in phi_x slots). 64*104 blocks.
__global__ __launch_bounds__(256) void k_nll_all(
    const us* dec_all, const us* dmW, const float* dmb, const float* x, float* nll)
{
  __shared__ alignas(16) char smemc[10256];
  const int b = blockIdx.x;
  const int t = b / 104;
  const int i = b - t * 104;
  const int bx = i % 13, by = i / 13;
  const us* dec = dec_all + (size_t)t * Bn * Hn;
  const float* xt = x + (size_t)t * Bn * Xn;

  us* As = (us*)smemc; us* Bs = (us*)(smemc + 5120);
  float* red = (float*)(smemc + 10240);
  const int tid = threadIdx.x, srow = tid >> 2, scb = (tid & 3) * 8;
  const int lane = tid & 63, w = tid >> 6, l15 = lane & 15, q = lane >> 4;
  const int m0 = by * 64, n0 = bx * 64;
  f32x4 acc[4];
  #pragma unroll
  for (int j = 0; j < 4; ++j) acc[j] = (f32x4){0.f, 0.f, 0.f, 0.f};
  const int wrow = (n0 + srow < Xn) ? (n0 + srow) : (Xn - 1);
  const us* ap = dec + (size_t)(m0 + srow) * Hn + scb;
  const us* wp = dmW + (size_t)wrow * Hn + scb;
  uint4 av = *(const uint4*)ap;
  uint4 wv = *(const uint4*)wp;
  for (int k0 = 0; k0 < Hn; k0 += 32) {
    __syncthreads();
    *(uint4*)&As[srow * 40 + scb] = av;
    *(uint4*)&Bs[srow * 40 + scb] = wv;
    __syncthreads();
    if (k0 + 32 < Hn) {
      av = *(const uint4*)(ap + k0 + 32);
      wv = *(const uint4*)(wp + k0 + 32);
    }
    bf16x8 a = *(const bf16x8*)&As[(w * 16 + l15) * 40 + q * 8];
    #pragma unroll
    for (int j = 0; j < 4; ++j) {
      bf16x8 bb = *(const bf16x8*)&Bs[(j * 16 + l15) * 40 + q * 8];
      acc[j] = __builtin_amdgcn_mfma_f32_16x16x32_bf16(a, bb, acc[j], 0, 0, 0);
    }
  }
  float sum = 0.0f;
  #pragma unroll
  for (int j = 0; j < 4; ++j) {
    const int n = n0 + j * 16 + l15;
    if (n < Xn) {
      const float bv = dmb[n];
      #pragma unroll
      for (int r = 0; r < 4; ++r) {
        const int m = m0 + w * 16 + q * 4 + r;
        const float a = acc[j][r] + bv;
        const float xv = xt[(size_t)m * Xn + n];
        sum += splusf(-a) + (1.0f - xv) * a;
      }
    }
  }
  const float s = block_sum(sum, red);
  if (tid == 0) atomicAdd(nll, s);
}

} // anonymous namespace

extern "C" void kernel_launch(void* const* d_in, const int* in_sizes, int n_in,
                              void* d_out, int out_size, void* d_ws, size_t ws_size,
                              hipStream_t stream)
{
  (void)in_sizes; (void)n_in; (void)out_size;
  const float* x     = (const float*)d_in[0];
  const float* eps_f = (const float*)d_in[1];
  const float* eps_z = (const float*)d_in[2];
  const float* pxW1  = (const float*)d_in[3];
  const float* pxb1  = (const float*)d_in[4];
  const float* pxW2  = (const float*)d_in[5];
  const float* pxb2  = (const float*)d_in[6];
  const float* pzW   = (const float*)d_in[7];
  const float* pzb   = (const float*)d_in[8];
  const float* pfW   = (const float*)d_in[9];
  const float* pfb   = (const float*)d_in[10];
  const float* rWih  = (const float*)d_in[11];
  const float* rWhh  = (const float*)d_in[12];
  const float* rbih  = (const float*)d_in[13];
  const float* rbhh  = (const float*)d_in[14];
  const float* zpW   = (const float*)d_in[15];
  const float* zpb   = (const float*)d_in[16];
  const float* zpmW  = (const float*)d_in[17];
  const float* zpmb  = (const float*)d_in[18];
  const float* zpsW  = (const float*)d_in[19];
  const float* zpsb  = (const float*)d_in[20];
  const float* feWih = (const float*)d_in[21];
  const float* feWhh = (const float*)d_in[22];
  const float* febih = (const float*)d_in[23];
  const float* febhh = (const float*)d_in[24];
  const float* femW  = (const float*)d_in[25];
  const float* femb  = (const float*)d_in[26];
  const float* fesW  = (const float*)d_in[27];
  const float* fesb  = (const float*)d_in[28];
  const float* zeW1  = (const float*)d_in[29];
  const float* zeb1  = (const float*)d_in[30];
  const float* zeW2  = (const float*)d_in[31];
  const float* zeb2  = (const float*)d_in[32];
  const float* zemW  = (const float*)d_in[33];
  const float* zemb  = (const float*)d_in[34];
  const float* zesW  = (const float*)d_in[35];
  const float* zesb  = (const float*)d_in[36];
  const float* dW1   = (const float*)d_in[37];
  const float* db1   = (const float*)d_in[38];
  const float* dW2   = (const float*)d_in[39];
  const float* db2   = (const float*)d_in[40];
  const float* dmW   = (const float*)d_in[41];
  const float* dmb   = (const float*)d_in[42];
  float* out = (float*)d_out;

  char* base = (char*)d_ws;
  size_t off = 0;
  auto ab = [&](size_t bytes) -> void* {
    void* p = base + off;
    off += (bytes + 255) & ~(size_t)255;
    return p;
  };

  // bf16 weights
  us* b_pxW1  = (us*)ab((size_t)512 * XnP * 2);
  us* b_pxW2  = (us*)ab((size_t)512 * 512 * 2);
  us* b_pzW   = (us*)ab((size_t)512 * 64 * 2);
  us* b_pfW   = (us*)ab((size_t)512 * 64 * 2);
  us* b_rWih  = (us*)ab((size_t)1536 * 1536 * 2);
  us* b_rWhh  = (us*)ab((size_t)1536 * 512 * 2);
  us* b_zpW   = (us*)ab((size_t)512 * 512 * 2);
  us* b_zpmW  = (us*)ab((size_t)64 * 512 * 2);
  us* b_zpsW  = (us*)ab((size_t)64 * 512 * 2);
  us* b_feWih = (us*)ab((size_t)1536 * 512 * 2);
  us* b_feWhh = (us*)ab((size_t)1536 * 512 * 2);
  us* b_femW  = (us*)ab((size_t)64 * 512 * 2);
  us* b_fesW  = (us*)ab((size_t)64 * 512 * 2);
  us* b_zeW1  = (us*)ab((size_t)512 * 1024 * 2);
  us* b_zeW2  = (us*)ab((size_t)512 * 512 * 2);
  us* b_zemW  = (us*)ab((size_t)64 * 512 * 2);
  us* b_zesW  = (us*)ab((size_t)64 * 512 * 2);
  us* b_dW1   = (us*)ab((size_t)512 * 1536 * 2);
  us* b_dW2   = (us*)ab((size_t)512 * 512 * 2);
  us* b_dmW   = (us*)ab((size_t)Xn * 512 * 2);

  // activations
  us* phi_x = (us*)ab((size_t)Tn * Bn * Hn * 2);  // doubles as dec_all in Phase D
  us* fh_a  = (us*)ab((size_t)Bn * Hn * 2);
  us* h_a   = (us*)ab((size_t)Bn * Hn * 2);   // adjacent to fh_a (one memset)
  us* fh_b  = (us*)ab((size_t)Bn * Hn * 2);
  us* h_b   = (us*)ab((size_t)Bn * Hn * 2);
  us* fbuf  = (us*)ab((size_t)Bn * Fn * 2);
  us* phi_f = (us*)ab((size_t)Bn * Hn * 2);
  us* zp    = (us*)ab((size_t)Bn * Hn * 2);
  us* zepre = (us*)ab((size_t)Bn * Hn * 2);
  us* ze    = (us*)ab((size_t)Bn * Hn * 2);
  us* phiz  = (us*)ab((size_t)Bn * Hn * 2);
  us* dtmp  = (us*)ab((size_t)Bn * Hn * 2);
  float* zpm = (float*)ab((size_t)Bn * Zn * 4);
  float* zps = (float*)ab((size_t)Bn * Zn * 4);
  float* Cpre_gru = (float*)ab((size_t)Bn * 1536 * 4);
  float* Cpre_dec = (float*)ab((size_t)Bn * 512 * 4);
  float* gipre    = (float*)ab((size_t)Bn * 1536 * 4);
  float* ghpre    = (float*)ab((size_t)Bn * 1536 * 4);
  float* dtmph    = (float*)ab((size_t)Bn * 512 * 4);

  int CH = 16;
  while (CH > 1 && off + (size_t)CH * (Bn * XnP + Bn * Hn) * 2 + 4096 > ws_size) CH >>= 1;
  us* xch  = (us*)ab((size_t)CH * Bn * XnP * 2);
  us* tmpb = (us*)ab((size_t)CH * Bn * Hn * 2);

  hipMemsetAsync(d_out, 0, 3 * sizeof(float), stream);
  hipMemsetAsync(fh_a, 0, 2 * (size_t)Bn * Hn * 2, stream);        // fh_a + h_a
  hipMemsetAsync(ghpre, 0, (size_t)Bn * 1536 * 4, stream);          // gh(h0=0) = 0

  const dim3 blk(256);

  // ---- one fused weight-convert kernel ----
  {
    CvtP cp;
    const float* srcs[19] = {pxW2, pzW, pfW, rWih, rWhh, zpW, zpmW, zpsW,
        feWih, feWhh, femW, fesW, zeW1, zeW2, zemW, zesW, dW1, dW2, dmW};
    us* dsts[19] = {b_pxW2, b_pzW, b_pfW, b_rWih, b_rWhh, b_zpW, b_zpmW, b_zpsW,
        b_feWih, b_feWhh, b_femW, b_fesW, b_zeW1, b_zeW2, b_zemW, b_zesW,
        b_dW1, b_dW2, b_dmW};
    const int ns[19] = {512*512, 512*64, 512*64, 1536*1536, 1536*512,
        512*512, 64*512, 64*512, 1536*512, 1536*512, 64*512, 64*512,
        512*1024, 512*512, 64*512, 64*512, 512*1536, 512*512, 784*512};
    for (int k = 0; k < 19; ++k) { cp.s[k] = srcs[k]; cp.d[k] = dsts[k]; cp.n[k] = ns[k]; }
    cp.pxW1src = pxW1; cp.pxW1dst = b_pxW1;
    k_cvt_all<<<dim3(1024), blk, 0, stream>>>(cp);
  }

  // ---- Phase A: phi_x ----
  for (int c = 0; c < Tn / CH; ++c) {
    const size_t nx = (size_t)CH * Bn * XnP;
    cvt_pad<<<dim3((unsigned)((nx + 255) / 256)), blk, 0, stream>>>(
        x + (size_t)c * CH * Bn * Xn, xch, Xn, XnP, (int)nx);
    const dim3 gA(8, CH * Bn / 64);
    k_gemmA<<<gA, blk, 0, stream>>>(xch, b_pxW1, XnP, XnP, pxb1, tmpb, Hn);
    k_gemmA<<<gA, blk, 0, stream>>>(tmpb, b_pxW2, Hn, Hn, pxb2,
                                    phi_x + (size_t)c * CH * Bn * Hn, Hn);
  }

  // ---- Phase B: f-encoder GRU ----
  us* fc = fh_a; us* fn2 = fh_b;
  for (int t = 0; t < Tn; ++t) {
    k_gruB<<<dim3(8, 8), blk, 0, stream>>>(
        phi_x + (size_t)t * Bn * Hn, b_feWih, fc, b_feWhh, febih, febhh, fn2);
    us* sw = fc; fc = fn2; fn2 = sw;
  }

  // ---- Phase C: f stats (final hidden back in fh_a since Tn even) ----
  k_statf<<<dim3(8), blk, 0, stream>>>(fh_a, b_femW, femb, b_fesW, fesb, eps_f, fbuf, out + 0);

  // ---- Prologue ----
  k_gemmA<<<dim3(8, 8), blk, 0, stream>>>(fbuf, b_pfW, Fn, Fn, pfb, phi_f, Hn);
  kP2<<<dim3(256), blk, 0, stream>>>(phi_f, b_rWih, b_dW1, db1, Cpre_gru, Cpre_dec);
  kP3<<<dim3(128), blk, 0, stream>>>(h_a, b_zpW, zpb, zp, phi_x, b_zeW1, zeb1, zepre);
  kP4<<<dim3(72), blk, 0, stream>>>(zepre, b_zeW2, zeb2, ze,
                                    zp, b_zpmW, zpmb, b_zpsW, zpsb, zpm, zps);

  // ---- Phase D: 4 launches per timestep; dec lands in phi_x[t] slot ----
  for (int t = 0; t < Tn; ++t) {
    const us* hcur = (t & 1) ? h_b : h_a;
    us* hnext      = (t & 1) ? h_a : h_b;
    const bool last = (t == Tn - 1);
    const us* px_t = phi_x + (size_t)t * Bn * Hn;

    kD1<<<dim3(200), blk, 0, stream>>>(
        ze, b_zemW, zemb, b_zesW, zesb, eps_z + (size_t)t * Bn * Zn, zpm, zps,
        b_pzW, pzb, phiz, out + 1, px_t, b_rWih, Cpre_gru, gipre);

    kD2<<<dim3(128), blk, 0, stream>>>(
        phiz, b_rWih, gipre, ghpre, hcur, rbih, rbhh, hnext,
        b_dW1, (t == 0 ? Cpre_dec : dtmph), dtmp);

    kD3<<<dim3(last ? 64 : 256), blk, 0, stream>>>(
        dtmp, b_dW2, db2, phi_x + (size_t)t * Bn * Hn,
        hnext, b_zpW, zpb, zp,
        phi_x + (size_t)(t + 1) * Bn * Hn, b_zeW1, zeb1, zepre,
        b_dW1, Cpre_dec, dtmph);

    if (!last)
      kD4<<<dim3(264), blk, 0, stream>>>(
          zepre, b_zeW2, zeb2, ze,
          zp, b_zpmW, zpmb, b_zpsW, zpsb, zpm, zps,
          hnext, b_rWhh, ghpre);
  }

  // ---- nll over all timesteps (fully parallel) ----
  k_nll_all<<<dim3(Tn * 104), blk, 0, stream>>>(phi_x, b_dmW, dmb, x, out + 2);
}